// Round 4
// baseline (2928.768 us; speedup 1.0000x reference)
//
#include <hip/hip_runtime.h>
#include <hip/hip_bf16.h>

// AAE_GCN round 4: f32 OUTPUT (reference returns jnp.float32 -> d_out is float*).
// r1-r3 wrote bf16; harness reads f32 -> decorrelated-but-plausible values,
// absmax 0.5356 = sqrt(2)*sigma*extreme ~= exactly the decorrelation signature.
// Pipeline = r2 fast paths (cross-validated bit-stable vs r3 naive build).
//
// ws layout (bytes, total 24,441,920):
//   xTt   [20000][128] f32 : 0
//   gcnTt [20000][128] f32 : 10,240,000
//   cnt   [20000] i32      : 20,480,000
//   offs  [20000] i32      : 20,560,000
//   cursor[20000] i32      : 20,640,000
//   dinv  [20000] f32      : 20,720,000
//   eSrc  [640000] i32     : 20,800,000
//   flag  i32              : 23,360,000
//   h1    [128][512] f32   : 23,360,064
//   h2    [128][256] f32   : 23,622,208
//   z     [128][64]  f32   : 23,753,280
//   d1    [128][256] f32   : 23,786,048
//   d2    [128][512] f32   : 23,917,120
//   g1    [128][256] f32   : 24,179,264
//   g2    [128][256] f32   : 24,310,336
//   dscr  [128]      f32   : 24,441,408

#define LRELU(v) ((v) > 0.f ? (v) : 0.01f * (v))

static constexpr int Bb = 512;
static constexpr int Nn = 20000;
static constexpr int Ee = 640000;
static constexpr int BT = 128;

// ---------- windowed fused transpose ----------
__global__ void transpose_win_k(const float* __restrict__ a, const float* __restrict__ nz,
                                float* __restrict__ out, int b0, int C) {
  __shared__ float tile[64][65];
  int c0 = blockIdx.x * 64;
  int rloc0 = blockIdx.y * 64;
  for (int i = threadIdx.x; i < 64 * 64; i += 256) {
    int rr = i >> 6, cc = i & 63;
    int r = b0 + rloc0 + rr, c = c0 + cc;
    float v = 0.f;
    if (c < C) {
      size_t idx = (size_t)r * C + c;
      v = a[idx] + 0.1f * nz[idx];
    }
    tile[rr][cc] = v;
  }
  __syncthreads();
  for (int i = threadIdx.x; i < 64 * 64; i += 256) {
    int cc = i >> 6, rr = i & 63;
    int c = c0 + cc;
    if (c < C) out[(size_t)c * BT + (rloc0 + rr)] = tile[rr][cc];
  }
}

// ---------- in-degree histogram + range check ----------
__global__ void hist_check_k(const int* __restrict__ src, const int* __restrict__ dst, int E,
                             int* __restrict__ cnt, int* __restrict__ flag) {
  int i = blockIdx.x * 256 + threadIdx.x;
  if (i < E) {
    int s = src[i], d = dst[i];
    if ((unsigned)s >= (unsigned)Nn || (unsigned)d >= (unsigned)Nn) {
      atomicExch(flag, 1);
    } else {
      atomicAdd(&cnt[d], 1);
    }
  }
}

// ---------- single-block scan: exclusive offsets, cursor copy, dinv ----------
__global__ void scan_k(const int* __restrict__ cnt, int N, int* __restrict__ off,
                       int* __restrict__ cursor, float* __restrict__ dinv) {
  __shared__ int s[1024];
  __shared__ int carry;
  if (threadIdx.x == 0) carry = 0;
  __syncthreads();
  for (int base = 0; base < N; base += 1024) {
    int i = base + threadIdx.x;
    int v = (i < N) ? cnt[i] : 0;
    s[threadIdx.x] = v;
    __syncthreads();
    for (int d = 1; d < 1024; d <<= 1) {
      int t = (threadIdx.x >= (unsigned)d) ? s[threadIdx.x - d] : 0;
      __syncthreads();
      s[threadIdx.x] += t;
      __syncthreads();
    }
    int excl = s[threadIdx.x] - v + carry;
    if (i < N) {
      off[i] = excl;
      cursor[i] = excl;
      dinv[i] = rsqrtf(2.0f + (float)v);  // deg = indeg + 2 (improved self-loop)
    }
    __syncthreads();
    if (threadIdx.x == 1023) carry += s[1023];
    __syncthreads();
  }
}

// ---------- scatter edges into CSR-by-dst ----------
__global__ void scatter_k(const int* __restrict__ src, const int* __restrict__ dst, int E,
                          int* __restrict__ cursor, int* __restrict__ eSrc) {
  int i = blockIdx.x * 256 + threadIdx.x;
  if (i < E) {
    int s = src[i], d = dst[i];
    if ((unsigned)s >= (unsigned)Nn || (unsigned)d >= (unsigned)Nn) return;
    int p = atomicAdd(&cursor[d], 1);
    eSrc[p] = s;
  }
}

// ---------- GCN gather + bias + lrelu over one batch tile ----------
__global__ void spmm_bt_k(const float* __restrict__ xTt, const int* __restrict__ eSrc,
                          const int* __restrict__ off, const int* __restrict__ cnt,
                          const float* __restrict__ dinv, const float* __restrict__ wg,
                          const float* __restrict__ bg, float* __restrict__ gcnTt) {
  int n = blockIdx.x;
  int b = threadIdx.x;  // 128 threads, one batch column each
  int o = off[n], c = cnt[n];
  float dn = dinv[n];
  float acc = 2.0f * dn * xTt[(size_t)n * BT + b];
  for (int i = 0; i < c; ++i) {
    int s = eSrc[o + i];
    acc += dinv[s] * xTt[(size_t)s * BT + b];
  }
  float v = wg[0] * dn * acc + bg[0];
  gcnTt[(size_t)n * BT + b] = LRELU(v);
}

// ---------- tiled f32 GEMM, A transposed (AT [K][M]), split-K atomic ----------
__global__ void gemm_splitk_AT(const float* __restrict__ AT, const float* __restrict__ B,
                               float* __restrict__ C, int M, int N, int K, int kChunk) {
  __shared__ float As[16][65];
  __shared__ float Bs[16][65];
  int m0 = blockIdx.y * 64, n0 = blockIdx.x * 64;
  int k0 = blockIdx.z * kChunk;
  int kEnd = min(K, k0 + kChunk);
  int tid = threadIdx.x;
  int tx = tid & 15, ty = tid >> 4;
  float acc[4][4] = {};
  for (int k = k0; k < kEnd; k += 16) {
    for (int i = tid; i < 64 * 16; i += 256) {
      int mm = i & 63, kk = i >> 6;
      As[kk][mm] = AT[(size_t)(k + kk) * M + (m0 + mm)];
    }
    for (int i = tid; i < 64 * 16; i += 256) {
      int nn = i & 63, kk = i >> 6;
      Bs[kk][nn] = B[(size_t)(k + kk) * N + (n0 + nn)];
    }
    __syncthreads();
    for (int kk = 0; kk < 16; ++kk) {
      float a[4], b[4];
#pragma unroll
      for (int i = 0; i < 4; ++i) a[i] = As[kk][ty * 4 + i];
#pragma unroll
      for (int j = 0; j < 4; ++j) b[j] = Bs[kk][tx * 4 + j];
#pragma unroll
      for (int i = 0; i < 4; ++i)
#pragma unroll
        for (int j = 0; j < 4; ++j) acc[i][j] += a[i] * b[j];
    }
    __syncthreads();
  }
#pragma unroll
  for (int i = 0; i < 4; ++i)
#pragma unroll
    for (int j = 0; j < 4; ++j) {
      int m = m0 + ty * 4 + i, n = n0 + tx * 4 + j;
      atomicAdd(&C[(size_t)m * N + n], acc[i][j]);
    }
}

// ---------- bias + lrelu in place ----------
__global__ void bias_act_k(float* __restrict__ C, const float* __restrict__ bias, int M, int N) {
  int i = blockIdx.x * 256 + threadIdx.x;
  if (i < M * N) {
    float v = C[i] + bias[i % N];
    C[i] = LRELU(v);
  }
}

// ---------- tiled f32 GEMM + bias + lrelu -> f32 out ----------
__global__ void gemm_bias_act_f32(const float* __restrict__ A, const float* __restrict__ B,
                                  const float* __restrict__ bias, float* __restrict__ C,
                                  int M, int N, int K) {
  __shared__ float As[16][65];
  __shared__ float Bs[16][65];
  int m0 = blockIdx.y * 64, n0 = blockIdx.x * 64;
  int tid = threadIdx.x;
  int tx = tid & 15, ty = tid >> 4;
  float acc[4][4] = {};
  for (int k = 0; k < K; k += 16) {
    for (int i = tid; i < 64 * 16; i += 256) {
      int kk = i & 15, mm = i >> 4;
      As[kk][mm] = A[(size_t)(m0 + mm) * K + (k + kk)];
    }
    for (int i = tid; i < 64 * 16; i += 256) {
      int nn = i & 63, kk = i >> 6;
      int n = n0 + nn;
      Bs[kk][nn] = (n < N) ? B[(size_t)(k + kk) * N + n] : 0.f;
    }
    __syncthreads();
    for (int kk = 0; kk < 16; ++kk) {
      float a[4], b[4];
#pragma unroll
      for (int i = 0; i < 4; ++i) a[i] = As[kk][ty * 4 + i];
#pragma unroll
      for (int j = 0; j < 4; ++j) b[j] = Bs[kk][tx * 4 + j];
#pragma unroll
      for (int i = 0; i < 4; ++i)
#pragma unroll
        for (int j = 0; j < 4; ++j) acc[i][j] += a[i] * b[j];
    }
    __syncthreads();
  }
#pragma unroll
  for (int i = 0; i < 4; ++i)
#pragma unroll
    for (int j = 0; j < 4; ++j) {
      int m = m0 + ty * 4 + i, n = n0 + tx * 4 + j;
      if (n < N) {
        float v = acc[i][j] + bias[n];
        C[(size_t)m * N + n] = LRELU(v);
      }
    }
}

// ---------- small FC (f32 mirror out) ----------
__global__ void fc_k(const float* __restrict__ A, const float* __restrict__ W,
                     const float* __restrict__ bias, float* __restrict__ C,
                     float* __restrict__ out_mirror, int N, int K, int act) {
  int j = blockIdx.x * blockDim.x + threadIdx.x;
  int b = blockIdx.y;
  if (j >= N) return;
  float acc = bias[j];
  const float* a = A + (size_t)b * K;
  for (int k = 0; k < K; ++k) acc += a[k] * W[(size_t)k * N + j];
  float v;
  if (act == 1)
    v = 1.f / (1.f + __expf(-acc));
  else
    v = LRELU(acc);
  C[(size_t)b * N + j] = v;
  if (out_mirror) out_mirror[(size_t)b * N + j] = v;
}

// ---------- sentinels ----------
__global__ void sentinel_k(float* out, float val) { out[0] = val; }
__global__ void flag_sentinel_k(float* out, const int* flag) {
  if (*flag != 0) out[0] = 70000.0f;
}

extern "C" void kernel_launch(void* const* d_in, const int* in_sizes, int n_in,
                              void* d_out, int out_size, void* d_ws, size_t ws_size,
                              hipStream_t stream) {
  const float* data = (const float*)d_in[0];
  const float* noise = (const float*)d_in[1];
  const int* edge = (const int*)d_in[2];
  const int* esrc_in = edge;       // edge_index[0]
  const int* edst_in = edge + Ee;  // edge_index[1]
  const float* w_gcn = (const float*)d_in[3];
  const float* b_gcn = (const float*)d_in[4];
  const float* enc1_w = (const float*)d_in[5];
  const float* enc1_b = (const float*)d_in[6];
  const float* enc2_w = (const float*)d_in[7];
  const float* enc2_b = (const float*)d_in[8];
  const float* enc3_w = (const float*)d_in[9];
  const float* enc3_b = (const float*)d_in[10];
  const float* dec1_w = (const float*)d_in[11];
  const float* dec1_b = (const float*)d_in[12];
  const float* dec2_w = (const float*)d_in[13];
  const float* dec2_b = (const float*)d_in[14];
  const float* dec3_w = (const float*)d_in[15];
  const float* dec3_b = (const float*)d_in[16];
  const float* disc1_w = (const float*)d_in[17];
  const float* disc1_b = (const float*)d_in[18];
  const float* disc2_w = (const float*)d_in[19];
  const float* disc2_b = (const float*)d_in[20];
  const float* disc3_w = (const float*)d_in[21];
  const float* disc3_b = (const float*)d_in[22];

  char* w = (char*)d_ws;
  float* xTt = (float*)(w + 0);
  float* gcnTt = (float*)(w + 10240000);
  int* cnt = (int*)(w + 20480000);
  int* offs = (int*)(w + 20560000);
  int* cursor = (int*)(w + 20640000);
  float* dinv = (float*)(w + 20720000);
  int* eSrc = (int*)(w + 20800000);
  int* flag = (int*)(w + 23360000);
  float* h1 = (float*)(w + 23360064);
  float* h2 = (float*)(w + 23622208);
  float* z = (float*)(w + 23753280);
  float* d1 = (float*)(w + 23786048);
  float* d2 = (float*)(w + 23917120);
  float* g1 = (float*)(w + 24179264);
  float* g2 = (float*)(w + 24310336);
  float* dscr = (float*)(w + 24441408);

  float* outp = (float*)d_out;               // f32 output!
  float* out_dec = outp;                     // [512][20000]
  float* out_z = outp + (size_t)Bb * Nn;     // [512][64]
  float* out_d = out_z + (size_t)Bb * 64;    // [512][1]

  // ---- host-side assumption checks -> sentinel ----
  static const int expect_sizes[23] = {
      10240000, 10240000, 1280000, 1, 1,
      10240000, 512, 131072, 256, 16384, 64,
      16384, 256, 131072, 512, 10240000, 20000,
      16384, 256, 65536, 256, 256, 1};
  float host_sentinel = 0.f;
  if (n_in != 23) host_sentinel = 50000.f;
  else if (out_size != 10273280) host_sentinel = 80000.f;
  else if (ws_size < 24441920u) host_sentinel = 60000.f;
  else {
    for (int i = 0; i < 23; ++i)
      if (in_sizes[i] != expect_sizes[i]) { host_sentinel = 100000.f + 1000.f * i; break; }
  }

  // ---- CSR build (once) ----
  hipMemsetAsync(cnt, 0, Nn * sizeof(int), stream);
  hipMemsetAsync(flag, 0, sizeof(int), stream);
  hist_check_k<<<(Ee + 255) / 256, 256, 0, stream>>>(esrc_in, edst_in, Ee, cnt, flag);
  scan_k<<<1, 1024, 0, stream>>>(cnt, Nn, offs, cursor, dinv);
  scatter_k<<<(Ee + 255) / 256, 256, 0, stream>>>(esrc_in, edst_in, Ee, cursor, eSrc);

  // ---- per batch-tile pipeline ----
  for (int b0 = 0; b0 < Bb; b0 += BT) {
    {
      dim3 g((Nn + 63) / 64, BT / 64);
      transpose_win_k<<<g, 256, 0, stream>>>(data, noise, xTt, b0, Nn);
    }
    spmm_bt_k<<<Nn, BT, 0, stream>>>(xTt, eSrc, offs, cnt, dinv, w_gcn, b_gcn, gcnTt);
    // h1 = lrelu(gcnTt^T @ enc1_w + b)   M=128 N=512 K=20000
    hipMemsetAsync(h1, 0, BT * 512 * sizeof(float), stream);
    {
      dim3 g(512 / 64, BT / 64, 25);
      gemm_splitk_AT<<<g, 256, 0, stream>>>(gcnTt, enc1_w, h1, BT, 512, Nn, 800);
      bias_act_k<<<(BT * 512 + 255) / 256, 256, 0, stream>>>(h1, enc1_b, BT, 512);
    }
    { dim3 g(1, BT); fc_k<<<g, 256, 0, stream>>>(h1, enc2_w, enc2_b, h2, nullptr, 256, 512, 0); }
    { dim3 g(1, BT); fc_k<<<g, 64, 0, stream>>>(h2, enc3_w, enc3_b, z, out_z + (size_t)b0 * 64, 64, 256, 0); }
    { dim3 g(1, BT); fc_k<<<g, 256, 0, stream>>>(z, dec1_w, dec1_b, d1, nullptr, 256, 64, 0); }
    { dim3 g(2, BT); fc_k<<<g, 256, 0, stream>>>(d1, dec2_w, dec2_b, d2, nullptr, 512, 256, 0); }
    // dec_h3 tile -> f32 out   M=128 N=20000 K=512
    {
      dim3 g((Nn + 63) / 64, BT / 64);
      gemm_bias_act_f32<<<g, 256, 0, stream>>>(d2, dec3_w, dec3_b, out_dec + (size_t)b0 * Nn,
                                               BT, Nn, 512);
    }
    { dim3 g(1, BT); fc_k<<<g, 256, 0, stream>>>(z, disc1_w, disc1_b, g1, nullptr, 256, 64, 0); }
    { dim3 g(1, BT); fc_k<<<g, 256, 0, stream>>>(g1, disc2_w, disc2_b, g2, nullptr, 256, 256, 0); }
    { dim3 g(1, BT); fc_k<<<g, 64, 0, stream>>>(g2, disc3_w, disc3_b, dscr, out_d + b0, 1, 256, 1); }
  }

  // ---- sentinels last ----
  flag_sentinel_k<<<1, 1, 0, stream>>>(out_dec, flag);
  if (host_sentinel != 0.f) sentinel_k<<<1, 1, 0, stream>>>(out_dec, host_sentinel);
}

// Round 5
// 510.443 us; speedup vs baseline: 5.7377x; 5.7377x over previous
//
#include <hip/hip_runtime.h>
#include <hip/hip_bf16.h>

// AAE_GCN round 5: single/dual-pass restructure + bf16 MFMA GEMMs.
//  - d_out is f32 (proven r4). Adaptive BT from ws_size (proven >= 24.44MB).
//  - enc1 (512x512xK20480 splitK) and dec3 (512x20000x512) via mfma 16x16x32 bf16.
//  - SpMM gathers bf16 (halved traffic). Fused tail kernel for all small FCs.

#define LRELU(v) ((v) > 0.f ? (v) : 0.01f * (v))

static constexpr int Bb = 512;
static constexpr int Nn = 20000;
static constexpr int Ee = 640000;
static constexpr int KPAD = 20480;  // enc1 K padded to 16*1280

typedef __attribute__((ext_vector_type(8))) short short8;
typedef __attribute__((ext_vector_type(4))) float f32x4;

__device__ __forceinline__ ushort f2bf(float f) {
  uint u = __builtin_bit_cast(uint, f);
  u = u + 0x7FFFu + ((u >> 16) & 1u);  // RTNE
  return (ushort)(u >> 16);
}
__device__ __forceinline__ float bf2f(ushort b) {
  return __builtin_bit_cast(float, ((uint)b) << 16);
}

// ---------- fused transpose + noise + bf16: rows [b0,b0+BT) -> xTbf[c][r-b0] ----------
__global__ void transpose_bf_k(const float* __restrict__ a, const float* __restrict__ nz,
                               ushort* __restrict__ out, int b0, int BT) {
  __shared__ ushort tile[64][65];
  int c0 = blockIdx.x * 64;
  int rloc0 = blockIdx.y * 64;
  for (int i = threadIdx.x; i < 64 * 64; i += 256) {
    int rr = i >> 6, cc = i & 63;
    int r = b0 + rloc0 + rr, c = c0 + cc;
    ushort v = 0;
    if (c < Nn) {
      size_t idx = (size_t)r * Nn + c;
      v = f2bf(a[idx] + 0.1f * nz[idx]);
    }
    tile[rr][cc] = v;
  }
  __syncthreads();
  for (int i = threadIdx.x; i < 64 * 64; i += 256) {
    int cc = i >> 6, rr = i & 63;
    int c = c0 + cc;
    if (c < Nn) out[(size_t)c * BT + (rloc0 + rr)] = tile[rr][cc];
  }
}

// ---------- degree histogram + range check ----------
__global__ void hist_check_k(const int* __restrict__ src, const int* __restrict__ dst, int E,
                             int* __restrict__ cnt, int* __restrict__ flag) {
  int i = blockIdx.x * 256 + threadIdx.x;
  if (i < E) {
    int s = src[i], d = dst[i];
    if ((unsigned)s >= (unsigned)Nn || (unsigned)d >= (unsigned)Nn) {
      atomicExch(flag, 1);
    } else {
      atomicAdd(&cnt[d], 1);
    }
  }
}

// ---------- single-block scan: exclusive offsets, cursor copy, dinv ----------
__global__ void scan_k(const int* __restrict__ cnt, int N, int* __restrict__ off,
                       int* __restrict__ cursor, float* __restrict__ dinv) {
  __shared__ int s[1024];
  __shared__ int carry;
  if (threadIdx.x == 0) carry = 0;
  __syncthreads();
  for (int base = 0; base < N; base += 1024) {
    int i = base + threadIdx.x;
    int v = (i < N) ? cnt[i] : 0;
    s[threadIdx.x] = v;
    __syncthreads();
    for (int d = 1; d < 1024; d <<= 1) {
      int t = (threadIdx.x >= (unsigned)d) ? s[threadIdx.x - d] : 0;
      __syncthreads();
      s[threadIdx.x] += t;
      __syncthreads();
    }
    int excl = s[threadIdx.x] - v + carry;
    if (i < N) {
      off[i] = excl;
      cursor[i] = excl;
      dinv[i] = rsqrtf(2.0f + (float)v);
    }
    __syncthreads();
    if (threadIdx.x == 1023) carry += s[1023];
    __syncthreads();
  }
}

// ---------- scatter edges into CSR-by-dst ----------
__global__ void scatter_k(const int* __restrict__ src, const int* __restrict__ dst, int E,
                          int* __restrict__ cursor, int* __restrict__ eSrc) {
  int i = blockIdx.x * 256 + threadIdx.x;
  if (i < E) {
    int s = src[i], d = dst[i];
    if ((unsigned)s >= (unsigned)Nn || (unsigned)d >= (unsigned)Nn) return;
    int p = atomicAdd(&cursor[d], 1);
    eSrc[p] = s;
  }
}

// ---------- GCN gather (bf16) + bias + lrelu: gcnT[n][0..BT) bf16 ----------
__global__ void spmm_bf_k(const ushort* __restrict__ xTbf, const int* __restrict__ eSrc,
                          const int* __restrict__ off, const int* __restrict__ cnt,
                          const float* __restrict__ dinv, const float* __restrict__ wg,
                          const float* __restrict__ bg, ushort* __restrict__ gcnT, int BT) {
  int n = blockIdx.x;
  int t = threadIdx.x;  // BT/2 threads, 2 cols each (packed uint)
  int o = off[n], c = cnt[n];
  float dn = dinv[n];
  uint su = *(const uint*)&xTbf[(size_t)n * BT + 2 * t];
  float acc0 = 2.0f * dn * bf2f((ushort)(su & 0xffff));
  float acc1 = 2.0f * dn * bf2f((ushort)(su >> 16));
  for (int i = 0; i < c; ++i) {
    int s = eSrc[o + i];
    float ds = dinv[s];
    uint u = *(const uint*)&xTbf[(size_t)s * BT + 2 * t];
    acc0 += ds * bf2f((ushort)(u & 0xffff));
    acc1 += ds * bf2f((ushort)(u >> 16));
  }
  float w = wg[0], bb = bg[0];
  float v0 = w * dn * acc0 + bb;
  float v1 = w * dn * acc1 + bb;
  v0 = LRELU(v0);
  v1 = LRELU(v1);
  uint pk = (uint)f2bf(v0) | ((uint)f2bf(v1) << 16);
  *(uint*)&gcnT[(size_t)n * BT + 2 * t] = pk;
}

// ---------- MFMA GEMM: C[M][N] = AT^T @ B.  AT [K][M] bf16 (lda), B [KB][N] f32 ----------
// Tile 64x64, BK=32, 4 waves (2x2), 16x16x32 bf16 fragments.
// SPLITK: atomicAdd f32 into C. else: C = lrelu(acc + bias[col]) direct store.
template <bool SPLITK>
__global__ __launch_bounds__(256) void mfma_gemm(const ushort* __restrict__ AT, int lda,
                                                 const float* __restrict__ B, int ldb, int KB,
                                                 int Nv, int iters, float* __restrict__ C,
                                                 int ldc, const float* __restrict__ bias) {
  __shared__ ushort As[32 * 72];
  __shared__ ushort Bs[32 * 72];
  int n0 = blockIdx.x * 64, m0 = blockIdx.y * 64;
  int k0 = blockIdx.z * iters * 32;
  int tid = threadIdx.x;
  int skk = tid >> 3, sx0 = (tid & 7) * 8;  // staging: k-row, 8-elem col group
  int l = tid & 63, w = tid >> 6;
  int wr = w >> 1, wc = w & 1;              // wave 2x2 arrangement
  int lrow = l & 15, lk8 = (l >> 4) * 8;
  f32x4 acc[2][2] = {};

  for (int kt = 0; kt < iters; ++kt) {
    int kg = k0 + kt * 32 + skk;
    // A: 16B bf16 load (AT padded/zeroed rows handle kg overrun for enc1; dec3 exact)
    uint4 av = *(const uint4*)&AT[(size_t)kg * lda + m0 + sx0];
    // B: 8 f32 -> bf16, guard k and col
    uint4 bv = {0u, 0u, 0u, 0u};
    if (kg < KB && n0 + sx0 < Nv) {
      const float4* bp = (const float4*)(B + (size_t)kg * ldb + n0 + sx0);
      float4 f0 = bp[0], f1 = bp[1];
      bv.x = (uint)f2bf(f0.x) | ((uint)f2bf(f0.y) << 16);
      bv.y = (uint)f2bf(f0.z) | ((uint)f2bf(f0.w) << 16);
      bv.z = (uint)f2bf(f1.x) | ((uint)f2bf(f1.y) << 16);
      bv.w = (uint)f2bf(f1.z) | ((uint)f2bf(f1.w) << 16);
    }
    __syncthreads();
    *(uint4*)&As[skk * 72 + sx0] = av;
    *(uint4*)&Bs[skk * 72 + sx0] = bv;
    __syncthreads();
    // fragments: lane l holds op[row=l&15][k=(l>>4)*8+j]
    short8 a0, a1, b0, b1;
#pragma unroll
    for (int j = 0; j < 8; ++j) {
      int kr = (lk8 + j) * 72;
      a0[j] = (short)As[kr + wr * 32 + lrow];
      a1[j] = (short)As[kr + wr * 32 + 16 + lrow];
      b0[j] = (short)Bs[kr + wc * 32 + lrow];
      b1[j] = (short)Bs[kr + wc * 32 + 16 + lrow];
    }
    acc[0][0] = __builtin_amdgcn_mfma_f32_16x16x32_bf16(a0, b0, acc[0][0], 0, 0, 0);
    acc[0][1] = __builtin_amdgcn_mfma_f32_16x16x32_bf16(a0, b1, acc[0][1], 0, 0, 0);
    acc[1][0] = __builtin_amdgcn_mfma_f32_16x16x32_bf16(a1, b0, acc[1][0], 0, 0, 0);
    acc[1][1] = __builtin_amdgcn_mfma_f32_16x16x32_bf16(a1, b1, acc[1][1], 0, 0, 0);
  }

  // epilogue: D col = lane&15, row = (lane>>4)*4 + reg
#pragma unroll
  for (int fm = 0; fm < 2; ++fm)
#pragma unroll
    for (int fn = 0; fn < 2; ++fn)
#pragma unroll
      for (int r = 0; r < 4; ++r) {
        int row = m0 + wr * 32 + fm * 16 + (l >> 4) * 4 + r;
        int col = n0 + wc * 32 + fn * 16 + lrow;
        if (SPLITK) {
          atomicAdd(&C[(size_t)row * ldc + col], acc[fm][fn][r]);
        } else if (col < Nv) {
          float v = acc[fm][fn][r] + bias[col];
          C[(size_t)row * ldc + col] = LRELU(v);
        }
      }
}

// ---------- bias + lrelu in place ----------
__global__ void bias_act_k(float* __restrict__ C, const float* __restrict__ bias, int total,
                           int N) {
  int i = blockIdx.x * 256 + threadIdx.x;
  if (i < total) {
    float v = C[i] + bias[i % N];
    C[i] = LRELU(v);
  }
}

// ---------- fused tail: h1 row -> h2 -> z -> d1 -> d2(bfT) ; z -> g1 -> g2 -> d ----------
__global__ __launch_bounds__(256) void tail_k(
    const float* __restrict__ h1, const float* __restrict__ W2, const float* __restrict__ c2,
    const float* __restrict__ W3, const float* __restrict__ c3, const float* __restrict__ Wd1,
    const float* __restrict__ cd1, const float* __restrict__ Wd2, const float* __restrict__ cd2,
    const float* __restrict__ Wg1, const float* __restrict__ cg1, const float* __restrict__ Wg2,
    const float* __restrict__ cg2, const float* __restrict__ Wg3, const float* __restrict__ cg3,
    float* __restrict__ out_z, float* __restrict__ out_d, ushort* __restrict__ d2bfT, int BT,
    int b0) {
  __shared__ float s_h1[512];
  __shared__ float s_h2[256];
  __shared__ float s_z[64];
  __shared__ float s_d1[256];
  __shared__ float s_g1[256];
  __shared__ float s_g2[256];
  __shared__ float s_red[4];
  int rl = blockIdx.x;
  int rg = b0 + rl;
  int t = threadIdx.x;

  s_h1[t] = h1[(size_t)rl * 512 + t];
  s_h1[t + 256] = h1[(size_t)rl * 512 + t + 256];
  __syncthreads();
  // h2 = lrelu(h1 @ W2 + c2)  K=512 N=256
  {
    float acc = c2[t];
#pragma unroll 4
    for (int k = 0; k < 512; ++k) acc += s_h1[k] * W2[(size_t)k * 256 + t];
    s_h2[t] = LRELU(acc);
  }
  __syncthreads();
  // z = lrelu(h2 @ W3 + c3)  K=256 N=64
  if (t < 64) {
    float acc = c3[t];
#pragma unroll 4
    for (int k = 0; k < 256; ++k) acc += s_h2[k] * W3[(size_t)k * 64 + t];
    float v = LRELU(acc);
    s_z[t] = v;
    out_z[(size_t)rg * 64 + t] = v;
  }
  __syncthreads();
  // d1 = lrelu(z @ Wd1 + cd1)  K=64 N=256
  {
    float acc = cd1[t];
#pragma unroll 4
    for (int k = 0; k < 64; ++k) acc += s_z[k] * Wd1[(size_t)k * 256 + t];
    s_d1[t] = LRELU(acc);
  }
  __syncthreads();
  // d2 = lrelu(d1 @ Wd2 + cd2)  K=256 N=512 -> transposed bf16 [feat][row]
  {
#pragma unroll
    for (int cc = 0; cc < 2; ++cc) {
      int c = t + cc * 256;
      float acc = cd2[c];
#pragma unroll 4
      for (int k = 0; k < 256; ++k) acc += s_d1[k] * Wd2[(size_t)k * 512 + c];
      float v = LRELU(acc);
      d2bfT[(size_t)c * BT + rl] = f2bf(v);
    }
  }
  // g1 = lrelu(z @ Wg1 + cg1)  K=64 N=256   (depends on s_z, already synced)
  {
    float acc = cg1[t];
#pragma unroll 4
    for (int k = 0; k < 64; ++k) acc += s_z[k] * Wg1[(size_t)k * 256 + t];
    s_g1[t] = LRELU(acc);
  }
  __syncthreads();
  // g2 = lrelu(g1 @ Wg2 + cg2)  K=256 N=256
  {
    float acc = cg2[t];
#pragma unroll 4
    for (int k = 0; k < 256; ++k) acc += s_g1[k] * Wg2[(size_t)k * 256 + t];
    s_g2[t] = LRELU(acc);
  }
  __syncthreads();
  // d = sigmoid(g2 @ Wg3 + cg3)  K=256 N=1
  {
    float p = s_g2[t] * Wg3[t];
#pragma unroll
    for (int o = 32; o > 0; o >>= 1) p += __shfl_down(p, o);
    if ((t & 63) == 0) s_red[t >> 6] = p;
    __syncthreads();
    if (t == 0) {
      float s = s_red[0] + s_red[1] + s_red[2] + s_red[3] + cg3[0];
      out_d[rg] = 1.f / (1.f + __expf(-s));
    }
  }
}

// ---------- sentinels ----------
__global__ void sentinel_k(float* out, float val) { out[0] = val; }
__global__ void flag_sentinel_k(float* out, const int* flag) {
  if (*flag != 0) out[0] = 70000.0f;
}

extern "C" void kernel_launch(void* const* d_in, const int* in_sizes, int n_in,
                              void* d_out, int out_size, void* d_ws, size_t ws_size,
                              hipStream_t stream) {
  const float* data = (const float*)d_in[0];
  const float* noise = (const float*)d_in[1];
  const int* edge = (const int*)d_in[2];
  const int* esrc_in = edge;
  const int* edst_in = edge + Ee;
  const float* w_gcn = (const float*)d_in[3];
  const float* b_gcn = (const float*)d_in[4];
  const float* enc1_w = (const float*)d_in[5];
  const float* enc1_b = (const float*)d_in[6];
  const float* enc2_w = (const float*)d_in[7];
  const float* enc2_b = (const float*)d_in[8];
  const float* enc3_w = (const float*)d_in[9];
  const float* enc3_b = (const float*)d_in[10];
  const float* dec1_w = (const float*)d_in[11];
  const float* dec1_b = (const float*)d_in[12];
  const float* dec2_w = (const float*)d_in[13];
  const float* dec2_b = (const float*)d_in[14];
  const float* dec3_w = (const float*)d_in[15];
  const float* dec3_b = (const float*)d_in[16];
  const float* disc1_w = (const float*)d_in[17];
  const float* disc1_b = (const float*)d_in[18];
  const float* disc2_w = (const float*)d_in[19];
  const float* disc2_b = (const float*)d_in[20];
  const float* disc3_w = (const float*)d_in[21];
  const float* disc3_b = (const float*)d_in[22];

  // ---- adaptive batch tile from ws_size (r4 proved ws >= 24,441,920) ----
  int BT = 128;
  if (ws_size >= 45910000u) BT = 512;
  else if (ws_size >= 24392300u) BT = 256;

  // ---- ws carve (16B aligned) ----
  char* w = (char*)d_ws;
  size_t o = 0;
  auto alloc = [&](size_t bytes) {
    size_t r = o;
    o = (o + bytes + 15) & ~(size_t)15;
    return r;
  };
  ushort* xTbf = (ushort*)(w + alloc((size_t)Nn * BT * 2));
  ushort* gcnT = (ushort*)(w + alloc((size_t)KPAD * BT * 2));
  float* h1 = (float*)(w + alloc((size_t)BT * 512 * 4));
  ushort* d2bfT = (ushort*)(w + alloc((size_t)512 * BT * 2));
  float* dinv = (float*)(w + alloc(Nn * 4));
  int* cnt = (int*)(w + alloc(Nn * 4));
  int* offs = (int*)(w + alloc(Nn * 4));
  int* cursor = (int*)(w + alloc(Nn * 4));
  int* eSrc = (int*)(w + alloc(Ee * 4));
  int* flag = (int*)(w + alloc(16));

  float* outp = (float*)d_out;
  float* out_dec = outp;                    // [512][20000]
  float* out_z = outp + (size_t)Bb * Nn;    // [512][64]
  float* out_d = out_z + (size_t)Bb * 64;   // [512]

  // ---- host sentinel ----
  static const int expect_sizes[23] = {
      10240000, 10240000, 1280000, 1, 1,
      10240000, 512, 131072, 256, 16384, 64,
      16384, 256, 131072, 512, 10240000, 20000,
      16384, 256, 65536, 256, 256, 1};
  float host_sentinel = 0.f;
  if (n_in != 23) host_sentinel = 50000.f;
  else if (out_size != 10273280) host_sentinel = 80000.f;
  else {
    for (int i = 0; i < 23; ++i)
      if (in_sizes[i] != expect_sizes[i]) { host_sentinel = 100000.f + 1000.f * i; break; }
  }

  // ---- CSR build (once) ----
  hipMemsetAsync(cnt, 0, Nn * sizeof(int), stream);
  hipMemsetAsync(flag, 0, sizeof(int), stream);
  hist_check_k<<<(Ee + 255) / 256, 256, 0, stream>>>(esrc_in, edst_in, Ee, cnt, flag);
  scan_k<<<1, 1024, 0, stream>>>(cnt, Nn, offs, cursor, dinv);
  scatter_k<<<(Ee + 255) / 256, 256, 0, stream>>>(esrc_in, edst_in, Ee, cursor, eSrc);
  // zero gcnT pad rows [20000, 20480)
  hipMemsetAsync(gcnT + (size_t)Nn * BT, 0, (size_t)(KPAD - Nn) * BT * 2, stream);

  // ---- per batch-tile pipeline ----
  for (int b0 = 0; b0 < Bb; b0 += BT) {
    {
      dim3 g((Nn + 63) / 64, BT / 64);
      transpose_bf_k<<<g, 256, 0, stream>>>(data, noise, xTbf, b0, BT);
    }
    spmm_bf_k<<<Nn, BT / 2, 0, stream>>>(xTbf, eSrc, offs, cnt, dinv, w_gcn, b_gcn, gcnT, BT);
    // enc1: h1[BT][512] = gcnT^T @ enc1_w, split-K 16x1280, then bias+lrelu
    hipMemsetAsync(h1, 0, (size_t)BT * 512 * 4, stream);
    {
      dim3 g(512 / 64, BT / 64, 16);
      mfma_gemm<true><<<g, 256, 0, stream>>>(gcnT, BT, enc1_w, 512, Nn, 512, 40, h1, 512,
                                             nullptr);
    }
    bias_act_k<<<(BT * 512 + 255) / 256, 256, 0, stream>>>(h1, enc1_b, BT * 512, 512);
    // fused tail: h2, z(out), d1, d2->d2bfT, g1, g2, d(out)
    tail_k<<<BT, 256, 0, stream>>>(h1, enc2_w, enc2_b, enc3_w, enc3_b, dec1_w, dec1_b, dec2_w,
                                   dec2_b, disc1_w, disc1_b, disc2_w, disc2_b, disc3_w, disc3_b,
                                   out_z, out_d, d2bfT, BT, b0);
    // dec3: out_dec rows [b0,b0+BT) = d2 @ dec3_w + bias, lrelu
    {
      dim3 g((Nn + 63) / 64, BT / 64, 1);
      mfma_gemm<false><<<g, 256, 0, stream>>>(d2bfT, BT, dec3_w, Nn, 512, Nn, 16,
                                              out_dec + (size_t)b0 * Nn, Nn, dec3_b);
    }
  }

  // ---- sentinels ----
  flag_sentinel_k<<<1, 1, 0, stream>>>(out_dec, flag);
  if (host_sentinel != 0.f) sentinel_k<<<1, 1, 0, stream>>>(out_dec, host_sentinel);
}

// Round 6
// 437.985 us; speedup vs baseline: 6.6869x; 1.1654x over previous
//
#include <hip/hip_runtime.h>
#include <hip/hip_bf16.h>

// AAE_GCN round 6: fix latency-serialized tail (182us/dispatch, VGPR=12, 263cy/iter).
// New tail2_k: float4 column groups + wave-split-K + LDS partial reduce -> pipelined loads.
// Everything else identical to passing r5 (510us).

#define LRELU(v) ((v) > 0.f ? (v) : 0.01f * (v))

static constexpr int Bb = 512;
static constexpr int Nn = 20000;
static constexpr int Ee = 640000;
static constexpr int KPAD = 20480;

typedef __attribute__((ext_vector_type(8))) short short8;
typedef __attribute__((ext_vector_type(4))) float f32x4;

__device__ __forceinline__ ushort f2bf(float f) {
  uint u = __builtin_bit_cast(uint, f);
  u = u + 0x7FFFu + ((u >> 16) & 1u);  // RTNE
  return (ushort)(u >> 16);
}
__device__ __forceinline__ float bf2f(ushort b) {
  return __builtin_bit_cast(float, ((uint)b) << 16);
}

// ---------- fused transpose + noise + bf16 ----------
__global__ void transpose_bf_k(const float* __restrict__ a, const float* __restrict__ nz,
                               ushort* __restrict__ out, int b0, int BT) {
  __shared__ ushort tile[64][65];
  int c0 = blockIdx.x * 64;
  int rloc0 = blockIdx.y * 64;
  for (int i = threadIdx.x; i < 64 * 64; i += 256) {
    int rr = i >> 6, cc = i & 63;
    int r = b0 + rloc0 + rr, c = c0 + cc;
    ushort v = 0;
    if (c < Nn) {
      size_t idx = (size_t)r * Nn + c;
      v = f2bf(a[idx] + 0.1f * nz[idx]);
    }
    tile[rr][cc] = v;
  }
  __syncthreads();
  for (int i = threadIdx.x; i < 64 * 64; i += 256) {
    int cc = i >> 6, rr = i & 63;
    int c = c0 + cc;
    if (c < Nn) out[(size_t)c * BT + (rloc0 + rr)] = tile[rr][cc];
  }
}

// ---------- degree histogram + range check ----------
__global__ void hist_check_k(const int* __restrict__ src, const int* __restrict__ dst, int E,
                             int* __restrict__ cnt, int* __restrict__ flag) {
  int i = blockIdx.x * 256 + threadIdx.x;
  if (i < E) {
    int s = src[i], d = dst[i];
    if ((unsigned)s >= (unsigned)Nn || (unsigned)d >= (unsigned)Nn) {
      atomicExch(flag, 1);
    } else {
      atomicAdd(&cnt[d], 1);
    }
  }
}

// ---------- single-block scan ----------
__global__ void scan_k(const int* __restrict__ cnt, int N, int* __restrict__ off,
                       int* __restrict__ cursor, float* __restrict__ dinv) {
  __shared__ int s[1024];
  __shared__ int carry;
  if (threadIdx.x == 0) carry = 0;
  __syncthreads();
  for (int base = 0; base < N; base += 1024) {
    int i = base + threadIdx.x;
    int v = (i < N) ? cnt[i] : 0;
    s[threadIdx.x] = v;
    __syncthreads();
    for (int d = 1; d < 1024; d <<= 1) {
      int t = (threadIdx.x >= (unsigned)d) ? s[threadIdx.x - d] : 0;
      __syncthreads();
      s[threadIdx.x] += t;
      __syncthreads();
    }
    int excl = s[threadIdx.x] - v + carry;
    if (i < N) {
      off[i] = excl;
      cursor[i] = excl;
      dinv[i] = rsqrtf(2.0f + (float)v);
    }
    __syncthreads();
    if (threadIdx.x == 1023) carry += s[1023];
    __syncthreads();
  }
}

// ---------- scatter edges into CSR-by-dst ----------
__global__ void scatter_k(const int* __restrict__ src, const int* __restrict__ dst, int E,
                          int* __restrict__ cursor, int* __restrict__ eSrc) {
  int i = blockIdx.x * 256 + threadIdx.x;
  if (i < E) {
    int s = src[i], d = dst[i];
    if ((unsigned)s >= (unsigned)Nn || (unsigned)d >= (unsigned)Nn) return;
    int p = atomicAdd(&cursor[d], 1);
    eSrc[p] = s;
  }
}

// ---------- GCN gather (bf16) + bias + lrelu ----------
__global__ void spmm_bf_k(const ushort* __restrict__ xTbf, const int* __restrict__ eSrc,
                          const int* __restrict__ off, const int* __restrict__ cnt,
                          const float* __restrict__ dinv, const float* __restrict__ wg,
                          const float* __restrict__ bg, ushort* __restrict__ gcnT, int BT) {
  int n = blockIdx.x;
  int t = threadIdx.x;
  int o = off[n], c = cnt[n];
  float dn = dinv[n];
  uint su = *(const uint*)&xTbf[(size_t)n * BT + 2 * t];
  float acc0 = 2.0f * dn * bf2f((ushort)(su & 0xffff));
  float acc1 = 2.0f * dn * bf2f((ushort)(su >> 16));
  for (int i = 0; i < c; ++i) {
    int s = eSrc[o + i];
    float ds = dinv[s];
    uint u = *(const uint*)&xTbf[(size_t)s * BT + 2 * t];
    acc0 += ds * bf2f((ushort)(u & 0xffff));
    acc1 += ds * bf2f((ushort)(u >> 16));
  }
  float w = wg[0], bb = bg[0];
  float v0 = w * dn * acc0 + bb;
  float v1 = w * dn * acc1 + bb;
  v0 = LRELU(v0);
  v1 = LRELU(v1);
  uint pk = (uint)f2bf(v0) | ((uint)f2bf(v1) << 16);
  *(uint*)&gcnT[(size_t)n * BT + 2 * t] = pk;
}

// ---------- MFMA GEMM (unchanged from r5, verified) ----------
template <bool SPLITK>
__global__ __launch_bounds__(256) void mfma_gemm(const ushort* __restrict__ AT, int lda,
                                                 const float* __restrict__ B, int ldb, int KB,
                                                 int Nv, int iters, float* __restrict__ C,
                                                 int ldc, const float* __restrict__ bias) {
  __shared__ ushort As[32 * 72];
  __shared__ ushort Bs[32 * 72];
  int n0 = blockIdx.x * 64, m0 = blockIdx.y * 64;
  int k0 = blockIdx.z * iters * 32;
  int tid = threadIdx.x;
  int skk = tid >> 3, sx0 = (tid & 7) * 8;
  int l = tid & 63, w = tid >> 6;
  int wr = w >> 1, wc = w & 1;
  int lrow = l & 15, lk8 = (l >> 4) * 8;
  f32x4 acc[2][2] = {};

  for (int kt = 0; kt < iters; ++kt) {
    int kg = k0 + kt * 32 + skk;
    uint4 av = *(const uint4*)&AT[(size_t)kg * lda + m0 + sx0];
    uint4 bv = {0u, 0u, 0u, 0u};
    if (kg < KB && n0 + sx0 < Nv) {
      const float4* bp = (const float4*)(B + (size_t)kg * ldb + n0 + sx0);
      float4 f0 = bp[0], f1 = bp[1];
      bv.x = (uint)f2bf(f0.x) | ((uint)f2bf(f0.y) << 16);
      bv.y = (uint)f2bf(f0.z) | ((uint)f2bf(f0.w) << 16);
      bv.z = (uint)f2bf(f1.x) | ((uint)f2bf(f1.y) << 16);
      bv.w = (uint)f2bf(f1.z) | ((uint)f2bf(f1.w) << 16);
    }
    __syncthreads();
    *(uint4*)&As[skk * 72 + sx0] = av;
    *(uint4*)&Bs[skk * 72 + sx0] = bv;
    __syncthreads();
    short8 a0, a1, b0, b1;
#pragma unroll
    for (int j = 0; j < 8; ++j) {
      int kr = (lk8 + j) * 72;
      a0[j] = (short)As[kr + wr * 32 + lrow];
      a1[j] = (short)As[kr + wr * 32 + 16 + lrow];
      b0[j] = (short)Bs[kr + wc * 32 + lrow];
      b1[j] = (short)Bs[kr + wc * 32 + 16 + lrow];
    }
    acc[0][0] = __builtin_amdgcn_mfma_f32_16x16x32_bf16(a0, b0, acc[0][0], 0, 0, 0);
    acc[0][1] = __builtin_amdgcn_mfma_f32_16x16x32_bf16(a0, b1, acc[0][1], 0, 0, 0);
    acc[1][0] = __builtin_amdgcn_mfma_f32_16x16x32_bf16(a1, b0, acc[1][0], 0, 0, 0);
    acc[1][1] = __builtin_amdgcn_mfma_f32_16x16x32_bf16(a1, b1, acc[1][1], 0, 0, 0);
  }

#pragma unroll
  for (int fm = 0; fm < 2; ++fm)
#pragma unroll
    for (int fn = 0; fn < 2; ++fn)
#pragma unroll
      for (int r = 0; r < 4; ++r) {
        int row = m0 + wr * 32 + fm * 16 + (l >> 4) * 4 + r;
        int col = n0 + wc * 32 + fn * 16 + lrow;
        if (SPLITK) {
          atomicAdd(&C[(size_t)row * ldc + col], acc[fm][fn][r]);
        } else if (col < Nv) {
          float v = acc[fm][fn][r] + bias[col];
          C[(size_t)row * ldc + col] = LRELU(v);
        }
      }
}

// ---------- bias + lrelu in place ----------
__global__ void bias_act_k(float* __restrict__ C, const float* __restrict__ bias, int total,
                           int N) {
  int i = blockIdx.x * 256 + threadIdx.x;
  if (i < total) {
    float v = C[i] + bias[i % N];
    C[i] = LRELU(v);
  }
}

// ---------- tail v2: ILP + wave-split-K. One block per batch row, 256 thr = 4 waves ----------
__global__ __launch_bounds__(256) void tail2_k(
    const float* __restrict__ h1, const float* __restrict__ W2, const float* __restrict__ c2,
    const float* __restrict__ W3, const float* __restrict__ c3, const float* __restrict__ Wd1,
    const float* __restrict__ cd1, const float* __restrict__ Wd2, const float* __restrict__ cd2,
    const float* __restrict__ Wg1, const float* __restrict__ cg1, const float* __restrict__ Wg2,
    const float* __restrict__ cg2, const float* __restrict__ Wg3, const float* __restrict__ cg3,
    float* __restrict__ out_z, float* __restrict__ out_d, ushort* __restrict__ d2bfT, int BT,
    int b0) {
  __shared__ float s_h1[512];
  __shared__ float s_h2[256];
  __shared__ float s_z[64];
  __shared__ float s_d1[256];
  __shared__ float s_g1[256];
  __shared__ float s_g2[256];
  __shared__ float s_part[4][256];  // K-split partials (viewed [2][512] for d2)
  __shared__ float s_red[4];
  int rl = blockIdx.x;
  int rg = b0 + rl;
  int t = threadIdx.x;
  int w = t >> 6, l = t & 63;

  s_h1[t] = h1[(size_t)rl * 512 + t];
  s_h1[t + 256] = h1[(size_t)rl * 512 + t + 256];
  __syncthreads();

  // ---- h2 = lrelu(h1 @ W2 + c2): N=256 K=512; wave w owns k in [128w,128w+128), lane l owns cols 4l..4l+3
  {
    int c4 = l * 4;
    float a0 = 0.f, a1 = 0.f, a2 = 0.f, a3 = 0.f;
#pragma unroll 8
    for (int k = w * 128; k < w * 128 + 128; ++k) {
      float4 wv = *(const float4*)&W2[(size_t)k * 256 + c4];
      float x = s_h1[k];
      a0 += x * wv.x; a1 += x * wv.y; a2 += x * wv.z; a3 += x * wv.w;
    }
    float4 pv = {a0, a1, a2, a3};
    *(float4*)&s_part[w][c4] = pv;
  }
  __syncthreads();
  s_h2[t] = LRELU(s_part[0][t] + s_part[1][t] + s_part[2][t] + s_part[3][t] + c2[t]);
  __syncthreads();

  // ---- z = lrelu(h2 @ W3 + c3): N=64 K=256; thread: col=t>>2, kpart=t&3 (64 iters)
  {
    int c = t >> 2, p = t & 3;
    float a = 0.f;
#pragma unroll 8
    for (int k = p * 64; k < p * 64 + 64; ++k) a += s_h2[k] * W3[(size_t)k * 64 + c];
    s_part[p][c] = a;
  }
  __syncthreads();
  if (t < 64) {
    float v = s_part[0][t] + s_part[1][t] + s_part[2][t] + s_part[3][t] + c3[t];
    v = LRELU(v);
    s_z[t] = v;
    out_z[(size_t)rg * 64 + t] = v;
  }
  __syncthreads();

  // ---- d1 = lrelu(z @ Wd1 + cd1): N=256 K=64; fully unrolled independent loads
  {
    float a = 0.f;
#pragma unroll
    for (int k = 0; k < 64; ++k) a += s_z[k] * Wd1[(size_t)k * 256 + t];
    s_d1[t] = LRELU(a + cd1[t]);
  }
  // ---- g1 = lrelu(z @ Wg1 + cg1): N=256 K=64 (also from s_z; no sync needed between)
  {
    float a = 0.f;
#pragma unroll
    for (int k = 0; k < 64; ++k) a += s_z[k] * Wg1[(size_t)k * 256 + t];
    s_g1[t] = LRELU(a + cg1[t]);
  }
  __syncthreads();

  // ---- d2 = lrelu(d1 @ Wd2 + cd2): N=512 K=256 -> bf16 transposed [feat][row]
  {
    int g = t & 127, p = t >> 7;  // col group 4g..4g+3, kpart p in {0,1} (128 iters)
    int c4 = g * 4;
    float a0 = 0.f, a1 = 0.f, a2 = 0.f, a3 = 0.f;
#pragma unroll 8
    for (int k = p * 128; k < p * 128 + 128; ++k) {
      float4 wv = *(const float4*)&Wd2[(size_t)k * 512 + c4];
      float x = s_d1[k];
      a0 += x * wv.x; a1 += x * wv.y; a2 += x * wv.z; a3 += x * wv.w;
    }
    float* sp = &s_part[0][0];
    float4 pv = {a0, a1, a2, a3};
    *(float4*)&sp[p * 512 + c4] = pv;
  }
  __syncthreads();
  {
    const float* sp = &s_part[0][0];
#pragma unroll
    for (int cc = 0; cc < 2; ++cc) {
      int c = t + cc * 256;
      float v = sp[c] + sp[512 + c] + cd2[c];
      v = LRELU(v);
      d2bfT[(size_t)c * BT + rl] = f2bf(v);
    }
  }
  __syncthreads();

  // ---- g2 = lrelu(g1 @ Wg2 + cg2): N=256 K=256; wave k-quarter (64 iters), float4 cols
  {
    int c4 = l * 4;
    float a0 = 0.f, a1 = 0.f, a2 = 0.f, a3 = 0.f;
#pragma unroll 8
    for (int k = w * 64; k < w * 64 + 64; ++k) {
      float4 wv = *(const float4*)&Wg2[(size_t)k * 256 + c4];
      float x = s_g1[k];
      a0 += x * wv.x; a1 += x * wv.y; a2 += x * wv.z; a3 += x * wv.w;
    }
    float4 pv = {a0, a1, a2, a3};
    *(float4*)&s_part[w][c4] = pv;
  }
  __syncthreads();
  s_g2[t] = LRELU(s_part[0][t] + s_part[1][t] + s_part[2][t] + s_part[3][t] + cg2[t]);
  __syncthreads();

  // ---- d = sigmoid(g2 . Wg3 + cg3)
  {
    float p = s_g2[t] * Wg3[t];
#pragma unroll
    for (int o = 32; o > 0; o >>= 1) p += __shfl_down(p, o);
    if ((t & 63) == 0) s_red[t >> 6] = p;
    __syncthreads();
    if (t == 0) {
      float s = s_red[0] + s_red[1] + s_red[2] + s_red[3] + cg3[0];
      out_d[rg] = 1.f / (1.f + __expf(-s));
    }
  }
}

// ---------- sentinels ----------
__global__ void sentinel_k(float* out, float val) { out[0] = val; }
__global__ void flag_sentinel_k(float* out, const int* flag) {
  if (*flag != 0) out[0] = 70000.0f;
}

extern "C" void kernel_launch(void* const* d_in, const int* in_sizes, int n_in,
                              void* d_out, int out_size, void* d_ws, size_t ws_size,
                              hipStream_t stream) {
  const float* data = (const float*)d_in[0];
  const float* noise = (const float*)d_in[1];
  const int* edge = (const int*)d_in[2];
  const int* esrc_in = edge;
  const int* edst_in = edge + Ee;
  const float* w_gcn = (const float*)d_in[3];
  const float* b_gcn = (const float*)d_in[4];
  const float* enc1_w = (const float*)d_in[5];
  const float* enc1_b = (const float*)d_in[6];
  const float* enc2_w = (const float*)d_in[7];
  const float* enc2_b = (const float*)d_in[8];
  const float* enc3_w = (const float*)d_in[9];
  const float* enc3_b = (const float*)d_in[10];
  const float* dec1_w = (const float*)d_in[11];
  const float* dec1_b = (const float*)d_in[12];
  const float* dec2_w = (const float*)d_in[13];
  const float* dec2_b = (const float*)d_in[14];
  const float* dec3_w = (const float*)d_in[15];
  const float* dec3_b = (const float*)d_in[16];
  const float* disc1_w = (const float*)d_in[17];
  const float* disc1_b = (const float*)d_in[18];
  const float* disc2_w = (const float*)d_in[19];
  const float* disc2_b = (const float*)d_in[20];
  const float* disc3_w = (const float*)d_in[21];
  const float* disc3_b = (const float*)d_in[22];

  int BT = 128;
  if (ws_size >= 45910000u) BT = 512;
  else if (ws_size >= 24392300u) BT = 256;

  char* w = (char*)d_ws;
  size_t o = 0;
  auto alloc = [&](size_t bytes) {
    size_t r = o;
    o = (o + bytes + 15) & ~(size_t)15;
    return r;
  };
  ushort* xTbf = (ushort*)(w + alloc((size_t)Nn * BT * 2));
  ushort* gcnT = (ushort*)(w + alloc((size_t)KPAD * BT * 2));
  float* h1 = (float*)(w + alloc((size_t)BT * 512 * 4));
  ushort* d2bfT = (ushort*)(w + alloc((size_t)512 * BT * 2));
  float* dinv = (float*)(w + alloc(Nn * 4));
  int* cnt = (int*)(w + alloc(Nn * 4));
  int* offs = (int*)(w + alloc(Nn * 4));
  int* cursor = (int*)(w + alloc(Nn * 4));
  int* eSrc = (int*)(w + alloc(Ee * 4));
  int* flag = (int*)(w + alloc(16));

  float* outp = (float*)d_out;
  float* out_dec = outp;
  float* out_z = outp + (size_t)Bb * Nn;
  float* out_d = out_z + (size_t)Bb * 64;

  static const int expect_sizes[23] = {
      10240000, 10240000, 1280000, 1, 1,
      10240000, 512, 131072, 256, 16384, 64,
      16384, 256, 131072, 512, 10240000, 20000,
      16384, 256, 65536, 256, 256, 1};
  float host_sentinel = 0.f;
  if (n_in != 23) host_sentinel = 50000.f;
  else if (out_size != 10273280) host_sentinel = 80000.f;
  else {
    for (int i = 0; i < 23; ++i)
      if (in_sizes[i] != expect_sizes[i]) { host_sentinel = 100000.f + 1000.f * i; break; }
  }

  // ---- CSR build (once) ----
  hipMemsetAsync(cnt, 0, Nn * sizeof(int), stream);
  hipMemsetAsync(flag, 0, sizeof(int), stream);
  hist_check_k<<<(Ee + 255) / 256, 256, 0, stream>>>(esrc_in, edst_in, Ee, cnt, flag);
  scan_k<<<1, 1024, 0, stream>>>(cnt, Nn, offs, cursor, dinv);
  scatter_k<<<(Ee + 255) / 256, 256, 0, stream>>>(esrc_in, edst_in, Ee, cursor, eSrc);
  hipMemsetAsync(gcnT + (size_t)Nn * BT, 0, (size_t)(KPAD - Nn) * BT * 2, stream);

  // ---- per batch-tile pipeline ----
  for (int b0 = 0; b0 < Bb; b0 += BT) {
    {
      dim3 g((Nn + 63) / 64, BT / 64);
      transpose_bf_k<<<g, 256, 0, stream>>>(data, noise, xTbf, b0, BT);
    }
    spmm_bf_k<<<Nn, BT / 2, 0, stream>>>(xTbf, eSrc, offs, cnt, dinv, w_gcn, b_gcn, gcnT, BT);
    hipMemsetAsync(h1, 0, (size_t)BT * 512 * 4, stream);
    {
      dim3 g(512 / 64, BT / 64, 16);
      mfma_gemm<true><<<g, 256, 0, stream>>>(gcnT, BT, enc1_w, 512, Nn, 512, 40, h1, 512,
                                             nullptr);
    }
    bias_act_k<<<(BT * 512 + 255) / 256, 256, 0, stream>>>(h1, enc1_b, BT * 512, 512);
    tail2_k<<<BT, 256, 0, stream>>>(h1, enc2_w, enc2_b, enc3_w, enc3_b, dec1_w, dec1_b, dec2_w,
                                    dec2_b, disc1_w, disc1_b, disc2_w, disc2_b, disc3_w,
                                    disc3_b, out_z, out_d, d2bfT, BT, b0);
    {
      dim3 g((Nn + 63) / 64, BT / 64, 1);
      mfma_gemm<false><<<g, 256, 0, stream>>>(d2bfT, BT, dec3_w, Nn, 512, Nn, 16,
                                              out_dec + (size_t)b0 * Nn, Nn, dec3_b);
    }
  }

  flag_sentinel_k<<<1, 1, 0, stream>>>(out_dec, flag);
  if (host_sentinel != 0.f) sentinel_k<<<1, 1, 0, stream>>>(out_dec, host_sentinel);
}

// Round 7
// 423.497 us; speedup vs baseline: 6.9157x; 1.0342x over previous
//
#include <hip/hip_runtime.h>
#include <hip/hip_bf16.h>

// AAE_GCN round 7: SpMM cache-panel rewrite.
//  r6 profile: spmm_bf_k 136.7us x2 = 62% of 438us, FETCH 274MB/dispatch
//  (27x re-fetch of 10.24MB gather set -> per-XCD L2 thrash) + VGPR=4 (no MLP).
//  Fix: 64-col panels (2.56MB, L2-resident), panel=bid%NP XCD affinity,
//  dinv folded into xs, 4-unrolled gather, ushort edge indices.

#define LRELU(v) ((v) > 0.f ? (v) : 0.01f * (v))

static constexpr int Bb = 512;
static constexpr int Nn = 20000;
static constexpr int Ee = 640000;
static constexpr int KPAD = 20480;

typedef __attribute__((ext_vector_type(8))) short short8;
typedef __attribute__((ext_vector_type(4))) float f32x4;

__device__ __forceinline__ ushort f2bf(float f) {
  uint u = __builtin_bit_cast(uint, f);
  u = u + 0x7FFFu + ((u >> 16) & 1u);  // RTNE
  return (ushort)(u >> 16);
}
__device__ __forceinline__ float bf2f(ushort b) {
  return __builtin_bit_cast(float, ((uint)b) << 16);
}

// ---------- transpose + noise + dinv-fold -> xs panels [p][Nn][64] bf16 ----------
__global__ void transpose_xs_k(const float* __restrict__ a, const float* __restrict__ nz,
                               const float* __restrict__ dinv, ushort* __restrict__ xs, int b0) {
  __shared__ ushort tile[64][65];
  int c0 = blockIdx.x * 64;      // node block
  int p = blockIdx.y;            // panel = batch-64-block within tile
  int rbase = b0 + p * 64;       // global batch row of lane 0
  for (int i = threadIdx.x; i < 64 * 64; i += 256) {
    int rr = i >> 6, cc = i & 63;
    int r = rbase + rr, c = c0 + cc;
    ushort v = 0;
    if (c < Nn) {
      size_t idx = (size_t)r * Nn + c;
      v = f2bf(dinv[c] * (a[idx] + 0.1f * nz[idx]));
    }
    tile[rr][cc] = v;
  }
  __syncthreads();
  for (int i = threadIdx.x; i < 64 * 64; i += 256) {
    int cc = i >> 6, rr = i & 63;
    int c = c0 + cc;
    if (c < Nn) xs[(size_t)p * Nn * 64 + (size_t)c * 64 + rr] = tile[rr][cc];
  }
}

// ---------- degree histogram + range check ----------
__global__ void hist_check_k(const int* __restrict__ src, const int* __restrict__ dst, int E,
                             int* __restrict__ cnt, int* __restrict__ flag) {
  int i = blockIdx.x * 256 + threadIdx.x;
  if (i < E) {
    int s = src[i], d = dst[i];
    if ((unsigned)s >= (unsigned)Nn || (unsigned)d >= (unsigned)Nn) {
      atomicExch(flag, 1);
    } else {
      atomicAdd(&cnt[d], 1);
    }
  }
}

// ---------- single-block scan ----------
__global__ void scan_k(const int* __restrict__ cnt, int N, int* __restrict__ off,
                       int* __restrict__ cursor, float* __restrict__ dinv) {
  __shared__ int s[1024];
  __shared__ int carry;
  if (threadIdx.x == 0) carry = 0;
  __syncthreads();
  for (int base = 0; base < N; base += 1024) {
    int i = base + threadIdx.x;
    int v = (i < N) ? cnt[i] : 0;
    s[threadIdx.x] = v;
    __syncthreads();
    for (int d = 1; d < 1024; d <<= 1) {
      int t = (threadIdx.x >= (unsigned)d) ? s[threadIdx.x - d] : 0;
      __syncthreads();
      s[threadIdx.x] += t;
      __syncthreads();
    }
    int excl = s[threadIdx.x] - v + carry;
    if (i < N) {
      off[i] = excl;
      cursor[i] = excl;
      dinv[i] = rsqrtf(2.0f + (float)v);
    }
    __syncthreads();
    if (threadIdx.x == 1023) carry += s[1023];
    __syncthreads();
  }
}

// ---------- scatter edges into CSR-by-dst (ushort src) ----------
__global__ void scatter_k(const int* __restrict__ src, const int* __restrict__ dst, int E,
                          int* __restrict__ cursor, ushort* __restrict__ eSrc) {
  int i = blockIdx.x * 256 + threadIdx.x;
  if (i < E) {
    int s = src[i], d = dst[i];
    if ((unsigned)s >= (unsigned)Nn || (unsigned)d >= (unsigned)Nn) return;
    int p = atomicAdd(&cursor[d], 1);
    eSrc[p] = (ushort)s;
  }
}

// ---------- panel SpMM: block = 4 waves x 4 nodes, panel = bid % NP ----------
// xs[p][n][l] holds bf16(dinv[n]*x[n][col]); acc = 2*xs[n] + sum_src xs[src];
// out = lrelu(w*dinv[n]*acc + b) -> gcnT[p][n][l]
__global__ __launch_bounds__(256) void spmm_panel_k(
    const ushort* __restrict__ xs, const ushort* __restrict__ eSrc, const int* __restrict__ offs,
    const int* __restrict__ cnt, const float* __restrict__ dinv, const float* __restrict__ wg,
    const float* __restrict__ bg, ushort* __restrict__ gcnT, int NP) {
  int bid = blockIdx.x;
  int panel = bid % NP;
  int ngrp = bid / NP;
  int wv = threadIdx.x >> 6, l = threadIdx.x & 63;
  int n = ngrp * 4 + wv;
  if (n >= Nn) return;
  int o = offs[n], c = cnt[n];
  const ushort* xrow = xs + (size_t)panel * ((size_t)Nn * 64) + l;
  float acc = 2.0f * bf2f(xrow[(size_t)n * 64]);
  const ushort* ep = eSrc + o;
  int i = 0;
  for (; i + 4 <= c; i += 4) {
    int s0 = ep[i], s1 = ep[i + 1], s2 = ep[i + 2], s3 = ep[i + 3];
    float v0 = bf2f(xrow[(size_t)s0 * 64]);
    float v1 = bf2f(xrow[(size_t)s1 * 64]);
    float v2 = bf2f(xrow[(size_t)s2 * 64]);
    float v3 = bf2f(xrow[(size_t)s3 * 64]);
    acc += (v0 + v1) + (v2 + v3);
  }
  for (; i < c; ++i) acc += bf2f(xrow[(size_t)ep[i] * 64]);
  float v = wg[0] * dinv[n] * acc + bg[0];
  v = LRELU(v);
  gcnT[(size_t)panel * ((size_t)KPAD * 64) + (size_t)n * 64 + l] = f2bf(v);
}

// ---------- MFMA GEMM with panel-strided A ----------
// A row addr = (m0>>6)*pstride + kg*lda + (m-m0).  enc1: lda=64, pstride=KPAD*64.
// dec3: lda=BT, pstride=64 (equivalent to dense [K][BT]).
template <bool SPLITK>
__global__ __launch_bounds__(256) void mfma_gemm(const ushort* __restrict__ AT, int lda,
                                                 size_t pstride, const float* __restrict__ B,
                                                 int ldb, int KB, int Nv, int iters,
                                                 float* __restrict__ C, int ldc,
                                                 const float* __restrict__ bias) {
  __shared__ ushort As[32 * 72];
  __shared__ ushort Bs[32 * 72];
  int n0 = blockIdx.x * 64, m0 = blockIdx.y * 64;
  int k0 = blockIdx.z * iters * 32;
  int tid = threadIdx.x;
  int skk = tid >> 3, sx0 = (tid & 7) * 8;
  int l = tid & 63, w = tid >> 6;
  int wr = w >> 1, wc = w & 1;
  int lrow = l & 15, lk8 = (l >> 4) * 8;
  const ushort* Ap = AT + (size_t)(m0 >> 6) * pstride;
  f32x4 acc[2][2] = {};

  for (int kt = 0; kt < iters; ++kt) {
    int kg = k0 + kt * 32 + skk;
    uint4 av = *(const uint4*)&Ap[(size_t)kg * lda + sx0];
    uint4 bv = {0u, 0u, 0u, 0u};
    if (kg < KB && n0 + sx0 < Nv) {
      const float4* bp = (const float4*)(B + (size_t)kg * ldb + n0 + sx0);
      float4 f0 = bp[0], f1 = bp[1];
      bv.x = (uint)f2bf(f0.x) | ((uint)f2bf(f0.y) << 16);
      bv.y = (uint)f2bf(f0.z) | ((uint)f2bf(f0.w) << 16);
      bv.z = (uint)f2bf(f1.x) | ((uint)f2bf(f1.y) << 16);
      bv.w = (uint)f2bf(f1.z) | ((uint)f2bf(f1.w) << 16);
    }
    __syncthreads();
    *(uint4*)&As[skk * 72 + sx0] = av;
    *(uint4*)&Bs[skk * 72 + sx0] = bv;
    __syncthreads();
    short8 a0, a1, b0, b1;
#pragma unroll
    for (int j = 0; j < 8; ++j) {
      int kr = (lk8 + j) * 72;
      a0[j] = (short)As[kr + wr * 32 + lrow];
      a1[j] = (short)As[kr + wr * 32 + 16 + lrow];
      b0[j] = (short)Bs[kr + wc * 32 + lrow];
      b1[j] = (short)Bs[kr + wc * 32 + 16 + lrow];
    }
    acc[0][0] = __builtin_amdgcn_mfma_f32_16x16x32_bf16(a0, b0, acc[0][0], 0, 0, 0);
    acc[0][1] = __builtin_amdgcn_mfma_f32_16x16x32_bf16(a0, b1, acc[0][1], 0, 0, 0);
    acc[1][0] = __builtin_amdgcn_mfma_f32_16x16x32_bf16(a1, b0, acc[1][0], 0, 0, 0);
    acc[1][1] = __builtin_amdgcn_mfma_f32_16x16x32_bf16(a1, b1, acc[1][1], 0, 0, 0);
  }

#pragma unroll
  for (int fm = 0; fm < 2; ++fm)
#pragma unroll
    for (int fn = 0; fn < 2; ++fn)
#pragma unroll
      for (int r = 0; r < 4; ++r) {
        int row = m0 + wr * 32 + fm * 16 + (l >> 4) * 4 + r;
        int col = n0 + wc * 32 + fn * 16 + lrow;
        if (SPLITK) {
          atomicAdd(&C[(size_t)row * ldc + col], acc[fm][fn][r]);
        } else if (col < Nv) {
          float v = acc[fm][fn][r] + bias[col];
          C[(size_t)row * ldc + col] = LRELU(v);
        }
      }
}

// ---------- bias + lrelu in place ----------
__global__ void bias_act_k(float* __restrict__ C, const float* __restrict__ bias, int total,
                           int N) {
  int i = blockIdx.x * 256 + threadIdx.x;
  if (i < total) {
    float v = C[i] + bias[i % N];
    C[i] = LRELU(v);
  }
}

// ---------- tail v2 (verified r6) ----------
__global__ __launch_bounds__(256) void tail2_k(
    const float* __restrict__ h1, const float* __restrict__ W2, const float* __restrict__ c2,
    const float* __restrict__ W3, const float* __restrict__ c3, const float* __restrict__ Wd1,
    const float* __restrict__ cd1, const float* __restrict__ Wd2, const float* __restrict__ cd2,
    const float* __restrict__ Wg1, const float* __restrict__ cg1, const float* __restrict__ Wg2,
    const float* __restrict__ cg2, const float* __restrict__ Wg3, const float* __restrict__ cg3,
    float* __restrict__ out_z, float* __restrict__ out_d, ushort* __restrict__ d2bfT, int BT,
    int b0) {
  __shared__ float s_h1[512];
  __shared__ float s_h2[256];
  __shared__ float s_z[64];
  __shared__ float s_d1[256];
  __shared__ float s_g1[256];
  __shared__ float s_g2[256];
  __shared__ float s_part[4][256];
  __shared__ float s_red[4];
  int rl = blockIdx.x;
  int rg = b0 + rl;
  int t = threadIdx.x;
  int w = t >> 6, l = t & 63;

  s_h1[t] = h1[(size_t)rl * 512 + t];
  s_h1[t + 256] = h1[(size_t)rl * 512 + t + 256];
  __syncthreads();

  {
    int c4 = l * 4;
    float a0 = 0.f, a1 = 0.f, a2 = 0.f, a3 = 0.f;
#pragma unroll 8
    for (int k = w * 128; k < w * 128 + 128; ++k) {
      float4 wv = *(const float4*)&W2[(size_t)k * 256 + c4];
      float x = s_h1[k];
      a0 += x * wv.x; a1 += x * wv.y; a2 += x * wv.z; a3 += x * wv.w;
    }
    float4 pv = {a0, a1, a2, a3};
    *(float4*)&s_part[w][c4] = pv;
  }
  __syncthreads();
  s_h2[t] = LRELU(s_part[0][t] + s_part[1][t] + s_part[2][t] + s_part[3][t] + c2[t]);
  __syncthreads();

  {
    int c = t >> 2, p = t & 3;
    float a = 0.f;
#pragma unroll 8
    for (int k = p * 64; k < p * 64 + 64; ++k) a += s_h2[k] * W3[(size_t)k * 64 + c];
    s_part[p][c] = a;
  }
  __syncthreads();
  if (t < 64) {
    float v = s_part[0][t] + s_part[1][t] + s_part[2][t] + s_part[3][t] + c3[t];
    v = LRELU(v);
    s_z[t] = v;
    out_z[(size_t)rg * 64 + t] = v;
  }
  __syncthreads();

  {
    float a = 0.f;
#pragma unroll
    for (int k = 0; k < 64; ++k) a += s_z[k] * Wd1[(size_t)k * 256 + t];
    s_d1[t] = LRELU(a + cd1[t]);
  }
  {
    float a = 0.f;
#pragma unroll
    for (int k = 0; k < 64; ++k) a += s_z[k] * Wg1[(size_t)k * 256 + t];
    s_g1[t] = LRELU(a + cg1[t]);
  }
  __syncthreads();

  {
    int g = t & 127, p = t >> 7;
    int c4 = g * 4;
    float a0 = 0.f, a1 = 0.f, a2 = 0.f, a3 = 0.f;
#pragma unroll 8
    for (int k = p * 128; k < p * 128 + 128; ++k) {
      float4 wv = *(const float4*)&Wd2[(size_t)k * 512 + c4];
      float x = s_d1[k];
      a0 += x * wv.x; a1 += x * wv.y; a2 += x * wv.z; a3 += x * wv.w;
    }
    float* sp = &s_part[0][0];
    float4 pv = {a0, a1, a2, a3};
    *(float4*)&sp[p * 512 + c4] = pv;
  }
  __syncthreads();
  {
    const float* sp = &s_part[0][0];
#pragma unroll
    for (int cc = 0; cc < 2; ++cc) {
      int c = t + cc * 256;
      float v = sp[c] + sp[512 + c] + cd2[c];
      v = LRELU(v);
      d2bfT[(size_t)c * BT + rl] = f2bf(v);
    }
  }
  __syncthreads();

  {
    int c4 = l * 4;
    float a0 = 0.f, a1 = 0.f, a2 = 0.f, a3 = 0.f;
#pragma unroll 8
    for (int k = w * 64; k < w * 64 + 64; ++k) {
      float4 wv = *(const float4*)&Wg2[(size_t)k * 256 + c4];
      float x = s_g1[k];
      a0 += x * wv.x; a1 += x * wv.y; a2 += x * wv.z; a3 += x * wv.w;
    }
    float4 pv = {a0, a1, a2, a3};
    *(float4*)&s_part[w][c4] = pv;
  }
  __syncthreads();
  s_g2[t] = LRELU(s_part[0][t] + s_part[1][t] + s_part[2][t] + s_part[3][t] + cg2[t]);
  __syncthreads();

  {
    float p = s_g2[t] * Wg3[t];
#pragma unroll
    for (int o = 32; o > 0; o >>= 1) p += __shfl_down(p, o);
    if ((t & 63) == 0) s_red[t >> 6] = p;
    __syncthreads();
    if (t == 0) {
      float s = s_red[0] + s_red[1] + s_red[2] + s_red[3] + cg3[0];
      out_d[rg] = 1.f / (1.f + __expf(-s));
    }
  }
}

// ---------- sentinels ----------
__global__ void sentinel_k(float* out, float val) { out[0] = val; }
__global__ void flag_sentinel_k(float* out, const int* flag) {
  if (*flag != 0) out[0] = 70000.0f;
}

extern "C" void kernel_launch(void* const* d_in, const int* in_sizes, int n_in,
                              void* d_out, int out_size, void* d_ws, size_t ws_size,
                              hipStream_t stream) {
  const float* data = (const float*)d_in[0];
  const float* noise = (const float*)d_in[1];
  const int* edge = (const int*)d_in[2];
  const int* esrc_in = edge;
  const int* edst_in = edge + Ee;
  const float* w_gcn = (const float*)d_in[3];
  const float* b_gcn = (const float*)d_in[4];
  const float* enc1_w = (const float*)d_in[5];
  const float* enc1_b = (const float*)d_in[6];
  const float* enc2_w = (const float*)d_in[7];
  const float* enc2_b = (const float*)d_in[8];
  const float* enc3_w = (const float*)d_in[9];
  const float* enc3_b = (const float*)d_in[10];
  const float* dec1_w = (const float*)d_in[11];
  const float* dec1_b = (const float*)d_in[12];
  const float* dec2_w = (const float*)d_in[13];
  const float* dec2_b = (const float*)d_in[14];
  const float* dec3_w = (const float*)d_in[15];
  const float* dec3_b = (const float*)d_in[16];
  const float* disc1_w = (const float*)d_in[17];
  const float* disc1_b = (const float*)d_in[18];
  const float* disc2_w = (const float*)d_in[19];
  const float* disc2_b = (const float*)d_in[20];
  const float* disc3_w = (const float*)d_in[21];
  const float* disc3_b = (const float*)d_in[22];

  // BT=512 needs ~44.63MB; BT=256 needs ~23.2MB (ws proven >= 24.44MB)
  int BT = 128;
  if (ws_size >= 44700000u) BT = 512;
  else if (ws_size >= 23200000u) BT = 256;
  int NP = BT / 64;

  char* w = (char*)d_ws;
  size_t o = 0;
  auto alloc = [&](size_t bytes) {
    size_t r = o;
    o = (o + bytes + 15) & ~(size_t)15;
    return r;
  };
  ushort* xs = (ushort*)(w + alloc((size_t)Nn * BT * 2));      // [NP][Nn][64]
  ushort* gcnT = (ushort*)(w + alloc((size_t)KPAD * BT * 2));  // [NP][KPAD][64]
  float* h1 = (float*)(w + alloc((size_t)BT * 512 * 4));
  ushort* d2bfT = (ushort*)(w + alloc((size_t)512 * BT * 2));
  float* dinv = (float*)(w + alloc(Nn * 4));
  int* cnt = (int*)(w + alloc(Nn * 4));
  int* offs = (int*)(w + alloc(Nn * 4));
  int* cursor = (int*)(w + alloc(Nn * 4));
  ushort* eSrc = (ushort*)(w + alloc(Ee * 2));
  int* flag = (int*)(w + alloc(16));

  float* outp = (float*)d_out;
  float* out_dec = outp;
  float* out_z = outp + (size_t)Bb * Nn;
  float* out_d = out_z + (size_t)Bb * 64;

  static const int expect_sizes[23] = {
      10240000, 10240000, 1280000, 1, 1,
      10240000, 512, 131072, 256, 16384, 64,
      16384, 256, 131072, 512, 10240000, 20000,
      16384, 256, 65536, 256, 256, 1};
  float host_sentinel = 0.f;
  if (n_in != 23) host_sentinel = 50000.f;
  else if (out_size != 10273280) host_sentinel = 80000.f;
  else {
    for (int i = 0; i < 23; ++i)
      if (in_sizes[i] != expect_sizes[i]) { host_sentinel = 100000.f + 1000.f * i; break; }
  }

  // ---- CSR build (once) ----
  hipMemsetAsync(cnt, 0, Nn * sizeof(int), stream);
  hipMemsetAsync(flag, 0, sizeof(int), stream);
  hist_check_k<<<(Ee + 255) / 256, 256, 0, stream>>>(esrc_in, edst_in, Ee, cnt, flag);
  scan_k<<<1, 1024, 0, stream>>>(cnt, Nn, offs, cursor, dinv);
  scatter_k<<<(Ee + 255) / 256, 256, 0, stream>>>(esrc_in, edst_in, Ee, cursor, eSrc);
  // zero full gcnT once (covers K-pad rows [Nn,KPAD) of every panel)
  hipMemsetAsync(gcnT, 0, (size_t)KPAD * BT * 2, stream);

  // ---- per batch-tile pipeline ----
  for (int b0 = 0; b0 < Bb; b0 += BT) {
    {
      dim3 g((Nn + 63) / 64, NP);
      transpose_xs_k<<<g, 256, 0, stream>>>(data, noise, dinv, xs, b0);
    }
    spmm_panel_k<<<(Nn / 4) * NP, 256, 0, stream>>>(xs, eSrc, offs, cnt, dinv, w_gcn, b_gcn,
                                                    gcnT, NP);
    hipMemsetAsync(h1, 0, (size_t)BT * 512 * 4, stream);
    {
      dim3 g(512 / 64, BT / 64, 16);
      mfma_gemm<true><<<g, 256, 0, stream>>>(gcnT, 64, (size_t)KPAD * 64, enc1_w, 512, Nn, 512,
                                             40, h1, 512, nullptr);
    }
    bias_act_k<<<(BT * 512 + 255) / 256, 256, 0, stream>>>(h1, enc1_b, BT * 512, 512);
    tail2_k<<<BT, 256, 0, stream>>>(h1, enc2_w, enc2_b, enc3_w, enc3_b, dec1_w, dec1_b, dec2_w,
                                    dec2_b, disc1_w, disc1_b, disc2_w, disc2_b, disc3_w,
                                    disc3_b, out_z, out_d, d2bfT, BT, b0);
    {
      dim3 g((Nn + 63) / 64, BT / 64, 1);
      mfma_gemm<false><<<g, 256, 0, stream>>>(d2bfT, BT, 64, dec3_w, Nn, 512, Nn, 16,
                                              out_dec + (size_t)b0 * Nn, Nn, dec3_b);
    }
  }

  flag_sentinel_k<<<1, 1, 0, stream>>>(out_dec, flag);
  if (host_sentinel != 0.f) sentinel_k<<<1, 1, 0, stream>>>(out_dec, host_sentinel);
}

// Round 8
// 368.902 us; speedup vs baseline: 7.9391x; 1.1480x over previous
//
#include <hip/hip_runtime.h>
#include <hip/hip_bf16.h>

// AAE_GCN round 8: SpMM MLP fix.
//  r7 profile: spmm_panel_k 125us x2 = 59% of 423us; FETCH fixed (16MB) but
//  VGPR=16 -> only 4 outstanding gathers, serial index->gather L2 round-trips.
//  Fix: wave loads whole edge list coalesced -> per-wave LDS -> 16-deep
//  unrolled gather batches into register array (16 loads in flight).

#define LRELU(v) ((v) > 0.f ? (v) : 0.01f * (v))

static constexpr int Bb = 512;
static constexpr int Nn = 20000;
static constexpr int Ee = 640000;
static constexpr int KPAD = 20480;

typedef __attribute__((ext_vector_type(8))) short short8;
typedef __attribute__((ext_vector_type(4))) float f32x4;

__device__ __forceinline__ ushort f2bf(float f) {
  uint u = __builtin_bit_cast(uint, f);
  u = u + 0x7FFFu + ((u >> 16) & 1u);  // RTNE
  return (ushort)(u >> 16);
}
__device__ __forceinline__ float bf2f(ushort b) {
  return __builtin_bit_cast(float, ((uint)b) << 16);
}

// ---------- transpose + noise + dinv-fold -> xs panels [p][Nn][64] bf16 ----------
__global__ void transpose_xs_k(const float* __restrict__ a, const float* __restrict__ nz,
                               const float* __restrict__ dinv, ushort* __restrict__ xs, int b0) {
  __shared__ ushort tile[64][65];
  int c0 = blockIdx.x * 64;
  int p = blockIdx.y;
  int rbase = b0 + p * 64;
  for (int i = threadIdx.x; i < 64 * 64; i += 256) {
    int rr = i >> 6, cc = i & 63;
    int r = rbase + rr, c = c0 + cc;
    ushort v = 0;
    if (c < Nn) {
      size_t idx = (size_t)r * Nn + c;
      v = f2bf(dinv[c] * (a[idx] + 0.1f * nz[idx]));
    }
    tile[rr][cc] = v;
  }
  __syncthreads();
  for (int i = threadIdx.x; i < 64 * 64; i += 256) {
    int cc = i >> 6, rr = i & 63;
    int c = c0 + cc;
    if (c < Nn) xs[(size_t)p * Nn * 64 + (size_t)c * 64 + rr] = tile[rr][cc];
  }
}

// ---------- degree histogram + range check ----------
__global__ void hist_check_k(const int* __restrict__ src, const int* __restrict__ dst, int E,
                             int* __restrict__ cnt, int* __restrict__ flag) {
  int i = blockIdx.x * 256 + threadIdx.x;
  if (i < E) {
    int s = src[i], d = dst[i];
    if ((unsigned)s >= (unsigned)Nn || (unsigned)d >= (unsigned)Nn) {
      atomicExch(flag, 1);
    } else {
      atomicAdd(&cnt[d], 1);
    }
  }
}

// ---------- single-block scan ----------
__global__ void scan_k(const int* __restrict__ cnt, int N, int* __restrict__ off,
                       int* __restrict__ cursor, float* __restrict__ dinv) {
  __shared__ int s[1024];
  __shared__ int carry;
  if (threadIdx.x == 0) carry = 0;
  __syncthreads();
  for (int base = 0; base < N; base += 1024) {
    int i = base + threadIdx.x;
    int v = (i < N) ? cnt[i] : 0;
    s[threadIdx.x] = v;
    __syncthreads();
    for (int d = 1; d < 1024; d <<= 1) {
      int t = (threadIdx.x >= (unsigned)d) ? s[threadIdx.x - d] : 0;
      __syncthreads();
      s[threadIdx.x] += t;
      __syncthreads();
    }
    int excl = s[threadIdx.x] - v + carry;
    if (i < N) {
      off[i] = excl;
      cursor[i] = excl;
      dinv[i] = rsqrtf(2.0f + (float)v);
    }
    __syncthreads();
    if (threadIdx.x == 1023) carry += s[1023];
    __syncthreads();
  }
}

// ---------- scatter edges into CSR-by-dst (ushort src) ----------
__global__ void scatter_k(const int* __restrict__ src, const int* __restrict__ dst, int E,
                          int* __restrict__ cursor, ushort* __restrict__ eSrc) {
  int i = blockIdx.x * 256 + threadIdx.x;
  if (i < E) {
    int s = src[i], d = dst[i];
    if ((unsigned)s >= (unsigned)Nn || (unsigned)d >= (unsigned)Nn) return;
    int p = atomicAdd(&cursor[d], 1);
    eSrc[p] = (ushort)s;
  }
}

// ---------- panel SpMM v2: index prefetch -> LDS, 16-deep gather batches ----------
__global__ __launch_bounds__(256) void spmm_panel_k(
    const ushort* __restrict__ xs, const ushort* __restrict__ eSrc, const int* __restrict__ offs,
    const int* __restrict__ cnt, const float* __restrict__ dinv, const float* __restrict__ wg,
    const float* __restrict__ bg, ushort* __restrict__ gcnT, int NP) {
  __shared__ ushort sIdx[4][64];
  int bid = blockIdx.x;
  int panel = bid % NP;
  int ngrp = bid / NP;
  int wv = threadIdx.x >> 6, l = threadIdx.x & 63;
  int n = ngrp * 4 + wv;
  if (n >= Nn) return;  // per-wave LDS rows, no cross-wave sync -> safe
  int o = offs[n], c = cnt[n];
  const ushort* xrow = xs + (size_t)panel * ((size_t)Nn * 64) + l;
  const ushort* ep = eSrc + o;
  float acc0 = 2.0f * bf2f(xrow[(size_t)n * 64]);
  float acc1 = 0.f, acc2 = 0.f, acc3 = 0.f;

  for (int base = 0; base < c; base += 64) {
    int rem = c - base;
    if (rem > 64) rem = 64;
    // wave-coalesced index load: lane l grabs index base+l
    sIdx[wv][l] = (l < rem) ? ep[base + l] : (ushort)0;
    // (same-wave LDS write->read; compiler inserts lgkmcnt wait)
    int i = 0;
    for (; i + 16 <= rem; i += 16) {
      float v[16];
#pragma unroll
      for (int j = 0; j < 16; ++j) {
        int s = sIdx[wv][i + j];
        v[j] = bf2f(xrow[(size_t)s * 64]);  // 16 independent 128B gathers
      }
#pragma unroll
      for (int j = 0; j < 16; j += 4) {
        acc0 += v[j];
        acc1 += v[j + 1];
        acc2 += v[j + 2];
        acc3 += v[j + 3];
      }
    }
    for (; i + 4 <= rem; i += 4) {
      int s0 = sIdx[wv][i], s1 = sIdx[wv][i + 1], s2 = sIdx[wv][i + 2], s3 = sIdx[wv][i + 3];
      float v0 = bf2f(xrow[(size_t)s0 * 64]);
      float v1 = bf2f(xrow[(size_t)s1 * 64]);
      float v2 = bf2f(xrow[(size_t)s2 * 64]);
      float v3 = bf2f(xrow[(size_t)s3 * 64]);
      acc0 += v0; acc1 += v1; acc2 += v2; acc3 += v3;
    }
    for (; i < rem; ++i) acc0 += bf2f(xrow[(size_t)sIdx[wv][i] * 64]);
  }

  float acc = (acc0 + acc1) + (acc2 + acc3);
  float v = wg[0] * dinv[n] * acc + bg[0];
  v = LRELU(v);
  gcnT[(size_t)panel * ((size_t)KPAD * 64) + (size_t)n * 64 + l] = f2bf(v);
}

// ---------- MFMA GEMM with panel-strided A (verified r7) ----------
template <bool SPLITK>
__global__ __launch_bounds__(256) void mfma_gemm(const ushort* __restrict__ AT, int lda,
                                                 size_t pstride, const float* __restrict__ B,
                                                 int ldb, int KB, int Nv, int iters,
                                                 float* __restrict__ C, int ldc,
                                                 const float* __restrict__ bias) {
  __shared__ ushort As[32 * 72];
  __shared__ ushort Bs[32 * 72];
  int n0 = blockIdx.x * 64, m0 = blockIdx.y * 64;
  int k0 = blockIdx.z * iters * 32;
  int tid = threadIdx.x;
  int skk = tid >> 3, sx0 = (tid & 7) * 8;
  int l = tid & 63, w = tid >> 6;
  int wr = w >> 1, wc = w & 1;
  int lrow = l & 15, lk8 = (l >> 4) * 8;
  const ushort* Ap = AT + (size_t)(m0 >> 6) * pstride;
  f32x4 acc[2][2] = {};

  for (int kt = 0; kt < iters; ++kt) {
    int kg = k0 + kt * 32 + skk;
    uint4 av = *(const uint4*)&Ap[(size_t)kg * lda + sx0];
    uint4 bv = {0u, 0u, 0u, 0u};
    if (kg < KB && n0 + sx0 < Nv) {
      const float4* bp = (const float4*)(B + (size_t)kg * ldb + n0 + sx0);
      float4 f0 = bp[0], f1 = bp[1];
      bv.x = (uint)f2bf(f0.x) | ((uint)f2bf(f0.y) << 16);
      bv.y = (uint)f2bf(f0.z) | ((uint)f2bf(f0.w) << 16);
      bv.z = (uint)f2bf(f1.x) | ((uint)f2bf(f1.y) << 16);
      bv.w = (uint)f2bf(f1.z) | ((uint)f2bf(f1.w) << 16);
    }
    __syncthreads();
    *(uint4*)&As[skk * 72 + sx0] = av;
    *(uint4*)&Bs[skk * 72 + sx0] = bv;
    __syncthreads();
    short8 a0, a1, b0, b1;
#pragma unroll
    for (int j = 0; j < 8; ++j) {
      int kr = (lk8 + j) * 72;
      a0[j] = (short)As[kr + wr * 32 + lrow];
      a1[j] = (short)As[kr + wr * 32 + 16 + lrow];
      b0[j] = (short)Bs[kr + wc * 32 + lrow];
      b1[j] = (short)Bs[kr + wc * 32 + 16 + lrow];
    }
    acc[0][0] = __builtin_amdgcn_mfma_f32_16x16x32_bf16(a0, b0, acc[0][0], 0, 0, 0);
    acc[0][1] = __builtin_amdgcn_mfma_f32_16x16x32_bf16(a0, b1, acc[0][1], 0, 0, 0);
    acc[1][0] = __builtin_amdgcn_mfma_f32_16x16x32_bf16(a1, b0, acc[1][0], 0, 0, 0);
    acc[1][1] = __builtin_amdgcn_mfma_f32_16x16x32_bf16(a1, b1, acc[1][1], 0, 0, 0);
  }

#pragma unroll
  for (int fm = 0; fm < 2; ++fm)
#pragma unroll
    for (int fn = 0; fn < 2; ++fn)
#pragma unroll
      for (int r = 0; r < 4; ++r) {
        int row = m0 + wr * 32 + fm * 16 + (l >> 4) * 4 + r;
        int col = n0 + wc * 32 + fn * 16 + lrow;
        if (SPLITK) {
          atomicAdd(&C[(size_t)row * ldc + col], acc[fm][fn][r]);
        } else if (col < Nv) {
          float v = acc[fm][fn][r] + bias[col];
          C[(size_t)row * ldc + col] = LRELU(v);
        }
      }
}

// ---------- bias + lrelu in place ----------
__global__ void bias_act_k(float* __restrict__ C, const float* __restrict__ bias, int total,
                           int N) {
  int i = blockIdx.x * 256 + threadIdx.x;
  if (i < total) {
    float v = C[i] + bias[i % N];
    C[i] = LRELU(v);
  }
}

// ---------- tail v2 (verified r6) ----------
__global__ __launch_bounds__(256) void tail2_k(
    const float* __restrict__ h1, const float* __restrict__ W2, const float* __restrict__ c2,
    const float* __restrict__ W3, const float* __restrict__ c3, const float* __restrict__ Wd1,
    const float* __restrict__ cd1, const float* __restrict__ Wd2, const float* __restrict__ cd2,
    const float* __restrict__ Wg1, const float* __restrict__ cg1, const float* __restrict__ Wg2,
    const float* __restrict__ cg2, const float* __restrict__ Wg3, const float* __restrict__ cg3,
    float* __restrict__ out_z, float* __restrict__ out_d, ushort* __restrict__ d2bfT, int BT,
    int b0) {
  __shared__ float s_h1[512];
  __shared__ float s_h2[256];
  __shared__ float s_z[64];
  __shared__ float s_d1[256];
  __shared__ float s_g1[256];
  __shared__ float s_g2[256];
  __shared__ float s_part[4][256];
  __shared__ float s_red[4];
  int rl = blockIdx.x;
  int rg = b0 + rl;
  int t = threadIdx.x;
  int w = t >> 6, l = t & 63;

  s_h1[t] = h1[(size_t)rl * 512 + t];
  s_h1[t + 256] = h1[(size_t)rl * 512 + t + 256];
  __syncthreads();

  {
    int c4 = l * 4;
    float a0 = 0.f, a1 = 0.f, a2 = 0.f, a3 = 0.f;
#pragma unroll 8
    for (int k = w * 128; k < w * 128 + 128; ++k) {
      float4 wv = *(const float4*)&W2[(size_t)k * 256 + c4];
      float x = s_h1[k];
      a0 += x * wv.x; a1 += x * wv.y; a2 += x * wv.z; a3 += x * wv.w;
    }
    float4 pv = {a0, a1, a2, a3};
    *(float4*)&s_part[w][c4] = pv;
  }
  __syncthreads();
  s_h2[t] = LRELU(s_part[0][t] + s_part[1][t] + s_part[2][t] + s_part[3][t] + c2[t]);
  __syncthreads();

  {
    int c = t >> 2, p = t & 3;
    float a = 0.f;
#pragma unroll 8
    for (int k = p * 64; k < p * 64 + 64; ++k) a += s_h2[k] * W3[(size_t)k * 64 + c];
    s_part[p][c] = a;
  }
  __syncthreads();
  if (t < 64) {
    float v = s_part[0][t] + s_part[1][t] + s_part[2][t] + s_part[3][t] + c3[t];
    v = LRELU(v);
    s_z[t] = v;
    out_z[(size_t)rg * 64 + t] = v;
  }
  __syncthreads();

  {
    float a = 0.f;
#pragma unroll
    for (int k = 0; k < 64; ++k) a += s_z[k] * Wd1[(size_t)k * 256 + t];
    s_d1[t] = LRELU(a + cd1[t]);
  }
  {
    float a = 0.f;
#pragma unroll
    for (int k = 0; k < 64; ++k) a += s_z[k] * Wg1[(size_t)k * 256 + t];
    s_g1[t] = LRELU(a + cg1[t]);
  }
  __syncthreads();

  {
    int g = t & 127, p = t >> 7;
    int c4 = g * 4;
    float a0 = 0.f, a1 = 0.f, a2 = 0.f, a3 = 0.f;
#pragma unroll 8
    for (int k = p * 128; k < p * 128 + 128; ++k) {
      float4 wv = *(const float4*)&Wd2[(size_t)k * 512 + c4];
      float x = s_d1[k];
      a0 += x * wv.x; a1 += x * wv.y; a2 += x * wv.z; a3 += x * wv.w;
    }
    float* sp = &s_part[0][0];
    float4 pv = {a0, a1, a2, a3};
    *(float4*)&sp[p * 512 + c4] = pv;
  }
  __syncthreads();
  {
    const float* sp = &s_part[0][0];
#pragma unroll
    for (int cc = 0; cc < 2; ++cc) {
      int c = t + cc * 256;
      float v = sp[c] + sp[512 + c] + cd2[c];
      v = LRELU(v);
      d2bfT[(size_t)c * BT + rl] = f2bf(v);
    }
  }
  __syncthreads();

  {
    int c4 = l * 4;
    float a0 = 0.f, a1 = 0.f, a2 = 0.f, a3 = 0.f;
#pragma unroll 8
    for (int k = w * 64; k < w * 64 + 64; ++k) {
      float4 wv = *(const float4*)&Wg2[(size_t)k * 256 + c4];
      float x = s_g1[k];
      a0 += x * wv.x; a1 += x * wv.y; a2 += x * wv.z; a3 += x * wv.w;
    }
    float4 pv = {a0, a1, a2, a3};
    *(float4*)&s_part[w][c4] = pv;
  }
  __syncthreads();
  s_g2[t] = LRELU(s_part[0][t] + s_part[1][t] + s_part[2][t] + s_part[3][t] + cg2[t]);
  __syncthreads();

  {
    float p = s_g2[t] * Wg3[t];
#pragma unroll
    for (int o = 32; o > 0; o >>= 1) p += __shfl_down(p, o);
    if ((t & 63) == 0) s_red[t >> 6] = p;
    __syncthreads();
    if (t == 0) {
      float s = s_red[0] + s_red[1] + s_red[2] + s_red[3] + cg3[0];
      out_d[rg] = 1.f / (1.f + __expf(-s));
    }
  }
}

// ---------- sentinels ----------
__global__ void sentinel_k(float* out, float val) { out[0] = val; }
__global__ void flag_sentinel_k(float* out, const int* flag) {
  if (*flag != 0) out[0] = 70000.0f;
}

extern "C" void kernel_launch(void* const* d_in, const int* in_sizes, int n_in,
                              void* d_out, int out_size, void* d_ws, size_t ws_size,
                              hipStream_t stream) {
  const float* data = (const float*)d_in[0];
  const float* noise = (const float*)d_in[1];
  const int* edge = (const int*)d_in[2];
  const int* esrc_in = edge;
  const int* edst_in = edge + Ee;
  const float* w_gcn = (const float*)d_in[3];
  const float* b_gcn = (const float*)d_in[4];
  const float* enc1_w = (const float*)d_in[5];
  const float* enc1_b = (const float*)d_in[6];
  const float* enc2_w = (const float*)d_in[7];
  const float* enc2_b = (const float*)d_in[8];
  const float* enc3_w = (const float*)d_in[9];
  const float* enc3_b = (const float*)d_in[10];
  const float* dec1_w = (const float*)d_in[11];
  const float* dec1_b = (const float*)d_in[12];
  const float* dec2_w = (const float*)d_in[13];
  const float* dec2_b = (const float*)d_in[14];
  const float* dec3_w = (const float*)d_in[15];
  const float* dec3_b = (const float*)d_in[16];
  const float* disc1_w = (const float*)d_in[17];
  const float* disc1_b = (const float*)d_in[18];
  const float* disc2_w = (const float*)d_in[19];
  const float* disc2_b = (const float*)d_in[20];
  const float* disc3_w = (const float*)d_in[21];
  const float* disc3_b = (const float*)d_in[22];

  int BT = 128;
  if (ws_size >= 44700000u) BT = 512;
  else if (ws_size >= 23200000u) BT = 256;
  int NP = BT / 64;

  char* w = (char*)d_ws;
  size_t o = 0;
  auto alloc = [&](size_t bytes) {
    size_t r = o;
    o = (o + bytes + 15) & ~(size_t)15;
    return r;
  };
  ushort* xs = (ushort*)(w + alloc((size_t)Nn * BT * 2));
  ushort* gcnT = (ushort*)(w + alloc((size_t)KPAD * BT * 2));
  float* h1 = (float*)(w + alloc((size_t)BT * 512 * 4));
  ushort* d2bfT = (ushort*)(w + alloc((size_t)512 * BT * 2));
  float* dinv = (float*)(w + alloc(Nn * 4));
  int* cnt = (int*)(w + alloc(Nn * 4));
  int* offs = (int*)(w + alloc(Nn * 4));
  int* cursor = (int*)(w + alloc(Nn * 4));
  ushort* eSrc = (ushort*)(w + alloc(Ee * 2));
  int* flag = (int*)(w + alloc(16));

  float* outp = (float*)d_out;
  float* out_dec = outp;
  float* out_z = outp + (size_t)Bb * Nn;
  float* out_d = out_z + (size_t)Bb * 64;

  static const int expect_sizes[23] = {
      10240000, 10240000, 1280000, 1, 1,
      10240000, 512, 131072, 256, 16384, 64,
      16384, 256, 131072, 512, 10240000, 20000,
      16384, 256, 65536, 256, 256, 1};
  float host_sentinel = 0.f;
  if (n_in != 23) host_sentinel = 50000.f;
  else if (out_size != 10273280) host_sentinel = 80000.f;
  else {
    for (int i = 0; i < 23; ++i)
      if (in_sizes[i] != expect_sizes[i]) { host_sentinel = 100000.f + 1000.f * i; break; }
  }

  // ---- CSR build (once) ----
  hipMemsetAsync(cnt, 0, Nn * sizeof(int), stream);
  hipMemsetAsync(flag, 0, sizeof(int), stream);
  hist_check_k<<<(Ee + 255) / 256, 256, 0, stream>>>(esrc_in, edst_in, Ee, cnt, flag);
  scan_k<<<1, 1024, 0, stream>>>(cnt, Nn, offs, cursor, dinv);
  scatter_k<<<(Ee + 255) / 256, 256, 0, stream>>>(esrc_in, edst_in, Ee, cursor, eSrc);
  hipMemsetAsync(gcnT, 0, (size_t)KPAD * BT * 2, stream);

  // ---- per batch-tile pipeline ----
  for (int b0 = 0; b0 < Bb; b0 += BT) {
    {
      dim3 g((Nn + 63) / 64, NP);
      transpose_xs_k<<<g, 256, 0, stream>>>(data, noise, dinv, xs, b0);
    }
    spmm_panel_k<<<(Nn / 4) * NP, 256, 0, stream>>>(xs, eSrc, offs, cnt, dinv, w_gcn, b_gcn,
                                                    gcnT, NP);
    hipMemsetAsync(h1, 0, (size_t)BT * 512 * 4, stream);
    {
      dim3 g(512 / 64, BT / 64, 16);
      mfma_gemm<true><<<g, 256, 0, stream>>>(gcnT, 64, (size_t)KPAD * 64, enc1_w, 512, Nn, 512,
                                             40, h1, 512, nullptr);
    }
    bias_act_k<<<(BT * 512 + 255) / 256, 256, 0, stream>>>(h1, enc1_b, BT * 512, 512);
    tail2_k<<<BT, 256, 0, stream>>>(h1, enc2_w, enc2_b, enc3_w, enc3_b, dec1_w, dec1_b, dec2_w,
                                    dec2_b, disc1_w, disc1_b, disc2_w, disc2_b, disc3_w,
                                    disc3_b, out_z, out_d, d2bfT, BT, b0);
    {
      dim3 g((Nn + 63) / 64, BT / 64, 1);
      mfma_gemm<false><<<g, 256, 0, stream>>>(d2bfT, BT, 64, dec3_w, Nn, 512, Nn, 16,
                                              out_dec + (size_t)b0 * Nn, Nn, dec3_b);
    }
  }

  flag_sentinel_k<<<1, 1, 0, stream>>>(out_dec, flag);
  if (host_sentinel != 0.f) sentinel_k<<<1, 1, 0, stream>>>(out_dec, host_sentinel);
}

// Round 9
// 329.944 us; speedup vs baseline: 8.8765x; 1.1181x over previous
//
#include <hip/hip_runtime.h>
#include <hip/hip_bf16.h>

// AAE_GCN round 9:
//  1) SpMM v3: 128-col chunks, uint gathers (2 cols/lane), pre-scaled byte-offset
//     indices -> ~1.7x fewer VALU instrs per edge. (r8: VALU-bound at 69%.)
//  2) scan_k (serial 16-wave block, est 25-40us) -> wave-bump offsets (order-free).
//  3) bias_act fused into tail2.

#define LRELU(v) ((v) > 0.f ? (v) : 0.01f * (v))

static constexpr int Bb = 512;
static constexpr int Nn = 20000;
static constexpr int Ee = 640000;
static constexpr int KPAD = 20480;

typedef __attribute__((ext_vector_type(8))) short short8;
typedef __attribute__((ext_vector_type(4))) float f32x4;

__device__ __forceinline__ ushort f2bf(float f) {
  uint u = __builtin_bit_cast(uint, f);
  u = u + 0x7FFFu + ((u >> 16) & 1u);  // RTNE
  return (ushort)(u >> 16);
}
__device__ __forceinline__ float bfLo(uint u) {
  return __builtin_bit_cast(float, u << 16);
}
__device__ __forceinline__ float bfHi(uint u) {
  return __builtin_bit_cast(float, u & 0xffff0000u);
}

// ---------- transpose + noise + dinv-fold -> xs chunks [NC][Nn][128] bf16 ----------
__global__ void transpose_xs_k(const float* __restrict__ a, const float* __restrict__ nz,
                               const float* __restrict__ dinv, ushort* __restrict__ xs, int b0) {
  __shared__ ushort tile[64][65];
  int c0 = blockIdx.x * 64;
  int p = blockIdx.y;              // 64-batch-row group within tile
  int chunk = p >> 1;              // 128-col chunk
  int sub = (p & 1) * 64;          // col offset within chunk
  int rbase = b0 + p * 64;
  for (int i = threadIdx.x; i < 64 * 64; i += 256) {
    int rr = i >> 6, cc = i & 63;
    int r = rbase + rr, c = c0 + cc;
    ushort v = 0;
    if (c < Nn) {
      size_t idx = (size_t)r * Nn + c;
      v = f2bf(dinv[c] * (a[idx] + 0.1f * nz[idx]));
    }
    tile[rr][cc] = v;
  }
  __syncthreads();
  for (int i = threadIdx.x; i < 64 * 64; i += 256) {
    int cc = i >> 6, rr = i & 63;
    int c = c0 + cc;
    if (c < Nn) xs[(size_t)chunk * Nn * 128 + (size_t)c * 128 + sub + rr] = tile[rr][cc];
  }
}

// ---------- degree histogram + range check ----------
__global__ void hist_check_k(const int* __restrict__ src, const int* __restrict__ dst, int E,
                             int* __restrict__ cnt, int* __restrict__ flag) {
  int i = blockIdx.x * 256 + threadIdx.x;
  if (i < E) {
    int s = src[i], d = dst[i];
    if ((unsigned)s >= (unsigned)Nn || (unsigned)d >= (unsigned)Nn) {
      atomicExch(flag, 1);
    } else {
      atomicAdd(&cnt[d], 1);
    }
  }
}

// ---------- offsets via wave prefix + atomic bump (order-free CSR) ----------
__global__ void offs_k(const int* __restrict__ cnt, int* __restrict__ offs,
                       int* __restrict__ cursor, float* __restrict__ dinv,
                       int* __restrict__ bump) {
  int i = blockIdx.x * 256 + threadIdx.x;
  int l = threadIdx.x & 63;
  int v = (i < Nn) ? cnt[i] : 0;
  int x = v;
#pragma unroll
  for (int d = 1; d < 64; d <<= 1) {
    int t = __shfl_up(x, d);
    if (l >= d) x += t;
  }
  int total = __shfl(x, 63);
  int base = 0;
  if (l == 0) base = atomicAdd(bump, total);
  base = __shfl(base, 0);
  int excl = base + x - v;
  if (i < Nn) {
    offs[i] = excl;
    cursor[i] = excl;
    dinv[i] = rsqrtf(2.0f + (float)v);
  }
}

// ---------- scatter edges into CSR-by-dst (pre-scaled byte offsets) ----------
__global__ void scatter_k(const int* __restrict__ src, const int* __restrict__ dst, int E,
                          int* __restrict__ cursor, uint* __restrict__ eOff) {
  int i = blockIdx.x * 256 + threadIdx.x;
  if (i < E) {
    int s = src[i], d = dst[i];
    if ((unsigned)s >= (unsigned)Nn || (unsigned)d >= (unsigned)Nn) return;
    int p = atomicAdd(&cursor[d], 1);
    eOff[p] = (uint)s * 256u;  // byte offset of 256B row
  }
}

// ---------- chunk SpMM: 128 cols/wave via uint gathers, 8-deep MLP ----------
__global__ __launch_bounds__(256) void spmm_chunk_k(
    const ushort* __restrict__ xs, const uint* __restrict__ eOff, const int* __restrict__ offs,
    const int* __restrict__ cnt, const float* __restrict__ dinv, const float* __restrict__ wg,
    const float* __restrict__ bg, ushort* __restrict__ gcnT, int NC) {
  __shared__ uint sIdx[4][64];
  int bid = blockIdx.x;
  int chunk = bid % NC;
  int ngrp = bid / NC;
  int wv = threadIdx.x >> 6, l = threadIdx.x & 63;
  int n = ngrp * 4 + wv;
  int o = offs[n], c = cnt[n];
  const char* base = (const char*)(xs + (size_t)chunk * Nn * 128) + l * 4;
  const uint* ep = eOff + o;
  uint su = *(const uint*)(base + (size_t)n * 256);
  float a00 = 2.0f * bfLo(su), a01 = 2.0f * bfHi(su);
  float a10 = 0.f, a11 = 0.f;

  for (int bi = 0; bi < c; bi += 64) {
    int rem = c - bi;
    if (rem > 64) rem = 64;
    sIdx[wv][l] = (l < rem) ? ep[bi + l] : 0u;
    int i = 0;
    for (; i + 8 <= rem; i += 8) {
      uint u[8];
#pragma unroll
      for (int j = 0; j < 8; ++j) u[j] = *(const uint*)(base + sIdx[wv][i + j]);
#pragma unroll
      for (int j = 0; j < 8; j += 2) {
        a00 += bfLo(u[j]);
        a01 += bfHi(u[j]);
        a10 += bfLo(u[j + 1]);
        a11 += bfHi(u[j + 1]);
      }
    }
    for (; i < rem; ++i) {
      uint u = *(const uint*)(base + sIdx[wv][i]);
      a00 += bfLo(u);
      a01 += bfHi(u);
    }
  }

  float wdn = wg[0] * dinv[n], bb = bg[0];
  float v0 = wdn * (a00 + a10) + bb;
  float v1 = wdn * (a01 + a11) + bb;
  v0 = LRELU(v0);
  v1 = LRELU(v1);
  uint pk = (uint)f2bf(v0) | ((uint)f2bf(v1) << 16);
  *(uint*)&gcnT[(size_t)chunk * KPAD * 128 + (size_t)n * 128 + 2 * l] = pk;
}

// ---------- MFMA GEMM, A chunk-strided: addr = (m0/pw)*pstride + kg*lda + m0%pw ----------
template <bool SPLITK>
__global__ __launch_bounds__(256) void mfma_gemm(const ushort* __restrict__ AT, int lda, int pw,
                                                 size_t pstride, const float* __restrict__ B,
                                                 int ldb, int KB, int Nv, int iters,
                                                 float* __restrict__ C, int ldc,
                                                 const float* __restrict__ bias) {
  __shared__ ushort As[32 * 72];
  __shared__ ushort Bs[32 * 72];
  int n0 = blockIdx.x * 64, m0 = blockIdx.y * 64;
  int k0 = blockIdx.z * iters * 32;
  int tid = threadIdx.x;
  int skk = tid >> 3, sx0 = (tid & 7) * 8;
  int l = tid & 63, w = tid >> 6;
  int wr = w >> 1, wc = w & 1;
  int lrow = l & 15, lk8 = (l >> 4) * 8;
  const ushort* Ap = AT + (size_t)(m0 / pw) * pstride + (m0 % pw);
  f32x4 acc[2][2] = {};

  for (int kt = 0; kt < iters; ++kt) {
    int kg = k0 + kt * 32 + skk;
    uint4 av = *(const uint4*)&Ap[(size_t)kg * lda + sx0];
    uint4 bv = {0u, 0u, 0u, 0u};
    if (kg < KB && n0 + sx0 < Nv) {
      const float4* bp = (const float4*)(B + (size_t)kg * ldb + n0 + sx0);
      float4 f0 = bp[0], f1 = bp[1];
      bv.x = (uint)f2bf(f0.x) | ((uint)f2bf(f0.y) << 16);
      bv.y = (uint)f2bf(f0.z) | ((uint)f2bf(f0.w) << 16);
      bv.z = (uint)f2bf(f1.x) | ((uint)f2bf(f1.y) << 16);
      bv.w = (uint)f2bf(f1.z) | ((uint)f2bf(f1.w) << 16);
    }
    __syncthreads();
    *(uint4*)&As[skk * 72 + sx0] = av;
    *(uint4*)&Bs[skk * 72 + sx0] = bv;
    __syncthreads();
    short8 a0, a1, b0, b1;
#pragma unroll
    for (int j = 0; j < 8; ++j) {
      int kr = (lk8 + j) * 72;
      a0[j] = (short)As[kr + wr * 32 + lrow];
      a1[j] = (short)As[kr + wr * 32 + 16 + lrow];
      b0[j] = (short)Bs[kr + wc * 32 + lrow];
      b1[j] = (short)Bs[kr + wc * 32 + 16 + lrow];
    }
    acc[0][0] = __builtin_amdgcn_mfma_f32_16x16x32_bf16(a0, b0, acc[0][0], 0, 0, 0);
    acc[0][1] = __builtin_amdgcn_mfma_f32_16x16x32_bf16(a0, b1, acc[0][1], 0, 0, 0);
    acc[1][0] = __builtin_amdgcn_mfma_f32_16x16x32_bf16(a1, b0, acc[1][0], 0, 0, 0);
    acc[1][1] = __builtin_amdgcn_mfma_f32_16x16x32_bf16(a1, b1, acc[1][1], 0, 0, 0);
  }

#pragma unroll
  for (int fm = 0; fm < 2; ++fm)
#pragma unroll
    for (int fn = 0; fn < 2; ++fn)
#pragma unroll
      for (int r = 0; r < 4; ++r) {
        int row = m0 + wr * 32 + fm * 16 + (l >> 4) * 4 + r;
        int col = n0 + wc * 32 + fn * 16 + lrow;
        if (SPLITK) {
          atomicAdd(&C[(size_t)row * ldc + col], acc[fm][fn][r]);
        } else if (col < Nv) {
          float v = acc[fm][fn][r] + bias[col];
          C[(size_t)row * ldc + col] = LRELU(v);
        }
      }
}

// ---------- tail v3: bias_act fused at h1 load (else = verified r6 tail2) ----------
__global__ __launch_bounds__(256) void tail2_k(
    const float* __restrict__ h1, const float* __restrict__ c1, const float* __restrict__ W2,
    const float* __restrict__ c2, const float* __restrict__ W3, const float* __restrict__ c3,
    const float* __restrict__ Wd1, const float* __restrict__ cd1, const float* __restrict__ Wd2,
    const float* __restrict__ cd2, const float* __restrict__ Wg1, const float* __restrict__ cg1,
    const float* __restrict__ Wg2, const float* __restrict__ cg2, const float* __restrict__ Wg3,
    const float* __restrict__ cg3, float* __restrict__ out_z, float* __restrict__ out_d,
    ushort* __restrict__ d2bfT, int BT, int b0) {
  __shared__ float s_h1[512];
  __shared__ float s_h2[256];
  __shared__ float s_z[64];
  __shared__ float s_d1[256];
  __shared__ float s_g1[256];
  __shared__ float s_g2[256];
  __shared__ float s_part[4][256];
  __shared__ float s_red[4];
  int rl = blockIdx.x;
  int rg = b0 + rl;
  int t = threadIdx.x;
  int w = t >> 6, l = t & 63;

  {
    float r0 = h1[(size_t)rl * 512 + t] + c1[t];
    float r1 = h1[(size_t)rl * 512 + t + 256] + c1[t + 256];
    s_h1[t] = LRELU(r0);
    s_h1[t + 256] = LRELU(r1);
  }
  __syncthreads();

  {
    int c4 = l * 4;
    float a0 = 0.f, a1 = 0.f, a2 = 0.f, a3 = 0.f;
#pragma unroll 8
    for (int k = w * 128; k < w * 128 + 128; ++k) {
      float4 wv = *(const float4*)&W2[(size_t)k * 256 + c4];
      float x = s_h1[k];
      a0 += x * wv.x; a1 += x * wv.y; a2 += x * wv.z; a3 += x * wv.w;
    }
    float4 pv = {a0, a1, a2, a3};
    *(float4*)&s_part[w][c4] = pv;
  }
  __syncthreads();
  s_h2[t] = LRELU(s_part[0][t] + s_part[1][t] + s_part[2][t] + s_part[3][t] + c2[t]);
  __syncthreads();

  {
    int c = t >> 2, p = t & 3;
    float a = 0.f;
#pragma unroll 8
    for (int k = p * 64; k < p * 64 + 64; ++k) a += s_h2[k] * W3[(size_t)k * 64 + c];
    s_part[p][c] = a;
  }
  __syncthreads();
  if (t < 64) {
    float v = s_part[0][t] + s_part[1][t] + s_part[2][t] + s_part[3][t] + c3[t];
    v = LRELU(v);
    s_z[t] = v;
    out_z[(size_t)rg * 64 + t] = v;
  }
  __syncthreads();

  {
    float a = 0.f;
#pragma unroll
    for (int k = 0; k < 64; ++k) a += s_z[k] * Wd1[(size_t)k * 256 + t];
    s_d1[t] = LRELU(a + cd1[t]);
  }
  {
    float a = 0.f;
#pragma unroll
    for (int k = 0; k < 64; ++k) a += s_z[k] * Wg1[(size_t)k * 256 + t];
    s_g1[t] = LRELU(a + cg1[t]);
  }
  __syncthreads();

  {
    int g = t & 127, p = t >> 7;
    int c4 = g * 4;
    float a0 = 0.f, a1 = 0.f, a2 = 0.f, a3 = 0.f;
#pragma unroll 8
    for (int k = p * 128; k < p * 128 + 128; ++k) {
      float4 wv = *(const float4*)&Wd2[(size_t)k * 512 + c4];
      float x = s_d1[k];
      a0 += x * wv.x; a1 += x * wv.y; a2 += x * wv.z; a3 += x * wv.w;
    }
    float* sp = &s_part[0][0];
    float4 pv = {a0, a1, a2, a3};
    *(float4*)&sp[p * 512 + c4] = pv;
  }
  __syncthreads();
  {
    const float* sp = &s_part[0][0];
#pragma unroll
    for (int cc = 0; cc < 2; ++cc) {
      int c = t + cc * 256;
      float v = sp[c] + sp[512 + c] + cd2[c];
      v = LRELU(v);
      d2bfT[(size_t)c * BT + rl] = f2bf(v);
    }
  }
  __syncthreads();

  {
    int c4 = l * 4;
    float a0 = 0.f, a1 = 0.f, a2 = 0.f, a3 = 0.f;
#pragma unroll 8
    for (int k = w * 64; k < w * 64 + 64; ++k) {
      float4 wv = *(const float4*)&Wg2[(size_t)k * 256 + c4];
      float x = s_g1[k];
      a0 += x * wv.x; a1 += x * wv.y; a2 += x * wv.z; a3 += x * wv.w;
    }
    float4 pv = {a0, a1, a2, a3};
    *(float4*)&s_part[w][c4] = pv;
  }
  __syncthreads();
  s_g2[t] = LRELU(s_part[0][t] + s_part[1][t] + s_part[2][t] + s_part[3][t] + cg2[t]);
  __syncthreads();

  {
    float p = s_g2[t] * Wg3[t];
#pragma unroll
    for (int o = 32; o > 0; o >>= 1) p += __shfl_down(p, o);
    if ((t & 63) == 0) s_red[t >> 6] = p;
    __syncthreads();
    if (t == 0) {
      float s = s_red[0] + s_red[1] + s_red[2] + s_red[3] + cg3[0];
      out_d[rg] = 1.f / (1.f + __expf(-s));
    }
  }
}

// ---------- sentinels ----------
__global__ void sentinel_k(float* out, float val) { out[0] = val; }
__global__ void flag_sentinel_k(float* out, const int* flag) {
  if (*flag != 0) out[0] = 70000.0f;
}

extern "C" void kernel_launch(void* const* d_in, const int* in_sizes, int n_in,
                              void* d_out, int out_size, void* d_ws, size_t ws_size,
                              hipStream_t stream) {
  const float* data = (const float*)d_in[0];
  const float* noise = (const float*)d_in[1];
  const int* edge = (const int*)d_in[2];
  const int* esrc_in = edge;
  const int* edst_in = edge + Ee;
  const float* w_gcn = (const float*)d_in[3];
  const float* b_gcn = (const float*)d_in[4];
  const float* enc1_w = (const float*)d_in[5];
  const float* enc1_b = (const float*)d_in[6];
  const float* enc2_w = (const float*)d_in[7];
  const float* enc2_b = (const float*)d_in[8];
  const float* enc3_w = (const float*)d_in[9];
  const float* enc3_b = (const float*)d_in[10];
  const float* dec1_w = (const float*)d_in[11];
  const float* dec1_b = (const float*)d_in[12];
  const float* dec2_w = (const float*)d_in[13];
  const float* dec2_b = (const float*)d_in[14];
  const float* dec3_w = (const float*)d_in[15];
  const float* dec3_b = (const float*)d_in[16];
  const float* disc1_w = (const float*)d_in[17];
  const float* disc1_b = (const float*)d_in[18];
  const float* disc2_w = (const float*)d_in[19];
  const float* disc2_b = (const float*)d_in[20];
  const float* disc3_w = (const float*)d_in[21];
  const float* disc3_b = (const float*)d_in[22];

  // BT=512 needs ~48.5MB; BT=256 needs ~24.40MB (ws proven >= 24.44MB)
  int BT = 128;
  if (ws_size >= 48500000u) BT = 512;
  else if (ws_size >= 24392500u) BT = 256;
  int NC = BT / 128;  // 128-col chunks per batch tile
  if (NC < 1) NC = 1;

  char* w = (char*)d_ws;
  size_t o = 0;
  auto alloc = [&](size_t bytes) {
    size_t r = o;
    o = (o + bytes + 15) & ~(size_t)15;
    return r;
  };
  ushort* xs = (ushort*)(w + alloc((size_t)Nn * BT * 2));      // [NC][Nn][128]
  ushort* gcnT = (ushort*)(w + alloc((size_t)KPAD * BT * 2));  // [NC][KPAD][128]
  float* h1 = (float*)(w + alloc((size_t)BT * 512 * 4));
  ushort* d2bfT = (ushort*)(w + alloc((size_t)512 * BT * 2));
  float* dinv = (float*)(w + alloc(Nn * 4));
  int* cnt = (int*)(w + alloc(Nn * 4));
  int* offs = (int*)(w + alloc(Nn * 4));
  int* cursor = (int*)(w + alloc(Nn * 4));
  uint* eOff = (uint*)(w + alloc(Ee * 4));
  int* flag = (int*)(w + alloc(16));  // [0]=range flag, [1]=bump counter

  float* outp = (float*)d_out;
  float* out_dec = outp;
  float* out_z = outp + (size_t)Bb * Nn;
  float* out_d = out_z + (size_t)Bb * 64;

  static const int expect_sizes[23] = {
      10240000, 10240000, 1280000, 1, 1,
      10240000, 512, 131072, 256, 16384, 64,
      16384, 256, 131072, 512, 10240000, 20000,
      16384, 256, 65536, 256, 256, 1};
  float host_sentinel = 0.f;
  if (n_in != 23) host_sentinel = 50000.f;
  else if (out_size != 10273280) host_sentinel = 80000.f;
  else {
    for (int i = 0; i < 23; ++i)
      if (in_sizes[i] != expect_sizes[i]) { host_sentinel = 100000.f + 1000.f * i; break; }
  }

  // ---- CSR build (once) ----
  hipMemsetAsync(cnt, 0, Nn * sizeof(int), stream);
  hipMemsetAsync(flag, 0, 2 * sizeof(int), stream);
  hist_check_k<<<(Ee + 255) / 256, 256, 0, stream>>>(esrc_in, edst_in, Ee, cnt, flag);
  offs_k<<<(Nn + 255) / 256, 256, 0, stream>>>(cnt, offs, cursor, dinv, flag + 1);
  scatter_k<<<(Ee + 255) / 256, 256, 0, stream>>>(esrc_in, edst_in, Ee, cursor, eOff);
  hipMemsetAsync(gcnT, 0, (size_t)KPAD * BT * 2, stream);

  // ---- per batch-tile pipeline ----
  for (int b0 = 0; b0 < Bb; b0 += BT) {
    {
      dim3 g((Nn + 63) / 64, BT / 64);
      transpose_xs_k<<<g, 256, 0, stream>>>(data, noise, dinv, xs, b0);
    }
    spmm_chunk_k<<<(Nn / 4) * NC, 256, 0, stream>>>(xs, eOff, offs, cnt, dinv, w_gcn, b_gcn,
                                                    gcnT, NC);
    hipMemsetAsync(h1, 0, (size_t)BT * 512 * 4, stream);
    {
      dim3 g(512 / 64, BT / 64, 16);
      mfma_gemm<true><<<g, 256, 0, stream>>>(gcnT, 128, 128, (size_t)KPAD * 128, enc1_w, 512,
                                             Nn, 512, 40, h1, 512, nullptr);
    }
    tail2_k<<<BT, 256, 0, stream>>>(h1, enc1_b, enc2_w, enc2_b, enc3_w, enc3_b, dec1_w, dec1_b,
                                    dec2_w, dec2_b, disc1_w, disc1_b, disc2_w, disc2_b, disc3_w,
                                    disc3_b, out_z, out_d, d2bfT, BT, b0);
    {
      dim3 g((Nn + 63) / 64, BT / 64, 1);
      mfma_gemm<false><<<g, 256, 0, stream>>>(d2bfT, BT, BT, 0, dec3_w, Nn, 512, Nn, 16,
                                              out_dec + (size_t)b0 * Nn, Nn, dec3_b);
    }
  }

  flag_sentinel_k<<<1, 1, 0, stream>>>(out_dec, flag);
  if (host_sentinel != 0.f) sentinel_k<<<1, 1, 0, stream>>>(out_dec, host_sentinel);
}

// Round 10
// 296.081 us; speedup vs baseline: 9.8918x; 1.1144x over previous
//
#include <hip/hip_runtime.h>
#include <hip/hip_bf16.h>

// AAE_GCN round 10: GEMM tile upgrade 64x64 -> 128x128 (4 waves x 64x64, 4x4 frags).
//  r9: 4 gemm dispatches x73.7us = 89% of 330us, MfmaUtil 5.5%, bank-conf 1e7.
//  - 64 MFMAs per barrier pair (was 16); B re-fetch 4x -> 2x.
//  - LDS k-row permutation p=(k&7)*4+(k>>3), stride 144 u16 (288B == 8 banks mod 32)
//    -> fragment reads land 2 lanes/bank (conflict-free), rows stay 16B-aligned.

#define LRELU(v) ((v) > 0.f ? (v) : 0.01f * (v))

static constexpr int Bb = 512;
static constexpr int Nn = 20000;
static constexpr int Ee = 640000;
static constexpr int KPAD = 20480;
static constexpr int LSTR = 144;  // LDS row stride in ushorts

typedef __attribute__((ext_vector_type(8))) short short8;
typedef __attribute__((ext_vector_type(4))) float f32x4;

__device__ __forceinline__ ushort f2bf(float f) {
  uint u = __builtin_bit_cast(uint, f);
  u = u + 0x7FFFu + ((u >> 16) & 1u);  // RTNE
  return (ushort)(u >> 16);
}
__device__ __forceinline__ float bfLo(uint u) {
  return __builtin_bit_cast(float, u << 16);
}
__device__ __forceinline__ float bfHi(uint u) {
  return __builtin_bit_cast(float, u & 0xffff0000u);
}

// ---------- transpose + noise + dinv-fold -> xs chunks [NC][Nn][128] bf16 ----------
__global__ void transpose_xs_k(const float* __restrict__ a, const float* __restrict__ nz,
                               const float* __restrict__ dinv, ushort* __restrict__ xs, int b0) {
  __shared__ ushort tile[64][65];
  int c0 = blockIdx.x * 64;
  int p = blockIdx.y;
  int chunk = p >> 1;
  int sub = (p & 1) * 64;
  int rbase = b0 + p * 64;
  for (int i = threadIdx.x; i < 64 * 64; i += 256) {
    int rr = i >> 6, cc = i & 63;
    int r = rbase + rr, c = c0 + cc;
    ushort v = 0;
    if (c < Nn) {
      size_t idx = (size_t)r * Nn + c;
      v = f2bf(dinv[c] * (a[idx] + 0.1f * nz[idx]));
    }
    tile[rr][cc] = v;
  }
  __syncthreads();
  for (int i = threadIdx.x; i < 64 * 64; i += 256) {
    int cc = i >> 6, rr = i & 63;
    int c = c0 + cc;
    if (c < Nn) xs[(size_t)chunk * Nn * 128 + (size_t)c * 128 + sub + rr] = tile[rr][cc];
  }
}

// ---------- degree histogram + range check ----------
__global__ void hist_check_k(const int* __restrict__ src, const int* __restrict__ dst, int E,
                             int* __restrict__ cnt, int* __restrict__ flag) {
  int i = blockIdx.x * 256 + threadIdx.x;
  if (i < E) {
    int s = src[i], d = dst[i];
    if ((unsigned)s >= (unsigned)Nn || (unsigned)d >= (unsigned)Nn) {
      atomicExch(flag, 1);
    } else {
      atomicAdd(&cnt[d], 1);
    }
  }
}

// ---------- offsets via wave prefix + atomic bump ----------
__global__ void offs_k(const int* __restrict__ cnt, int* __restrict__ offs,
                       int* __restrict__ cursor, float* __restrict__ dinv,
                       int* __restrict__ bump) {
  int i = blockIdx.x * 256 + threadIdx.x;
  int l = threadIdx.x & 63;
  int v = (i < Nn) ? cnt[i] : 0;
  int x = v;
#pragma unroll
  for (int d = 1; d < 64; d <<= 1) {
    int t = __shfl_up(x, d);
    if (l >= d) x += t;
  }
  int total = __shfl(x, 63);
  int base = 0;
  if (l == 0) base = atomicAdd(bump, total);
  base = __shfl(base, 0);
  int excl = base + x - v;
  if (i < Nn) {
    offs[i] = excl;
    cursor[i] = excl;
    dinv[i] = rsqrtf(2.0f + (float)v);
  }
}

// ---------- scatter edges (pre-scaled byte offsets) ----------
__global__ void scatter_k(const int* __restrict__ src, const int* __restrict__ dst, int E,
                          int* __restrict__ cursor, uint* __restrict__ eOff) {
  int i = blockIdx.x * 256 + threadIdx.x;
  if (i < E) {
    int s = src[i], d = dst[i];
    if ((unsigned)s >= (unsigned)Nn || (unsigned)d >= (unsigned)Nn) return;
    int p = atomicAdd(&cursor[d], 1);
    eOff[p] = (uint)s * 256u;
  }
}

// ---------- chunk SpMM (verified r9) ----------
__global__ __launch_bounds__(256) void spmm_chunk_k(
    const ushort* __restrict__ xs, const uint* __restrict__ eOff, const int* __restrict__ offs,
    const int* __restrict__ cnt, const float* __restrict__ dinv, const float* __restrict__ wg,
    const float* __restrict__ bg, ushort* __restrict__ gcnT, int NC) {
  __shared__ uint sIdx[4][64];
  int bid = blockIdx.x;
  int chunk = bid % NC;
  int ngrp = bid / NC;
  int wv = threadIdx.x >> 6, l = threadIdx.x & 63;
  int n = ngrp * 4 + wv;
  int o = offs[n], c = cnt[n];
  const char* base = (const char*)(xs + (size_t)chunk * Nn * 128) + l * 4;
  const uint* ep = eOff + o;
  uint su = *(const uint*)(base + (size_t)n * 256);
  float a00 = 2.0f * bfLo(su), a01 = 2.0f * bfHi(su);
  float a10 = 0.f, a11 = 0.f;

  for (int bi = 0; bi < c; bi += 64) {
    int rem = c - bi;
    if (rem > 64) rem = 64;
    sIdx[wv][l] = (l < rem) ? ep[bi + l] : 0u;
    int i = 0;
    for (; i + 8 <= rem; i += 8) {
      uint u[8];
#pragma unroll
      for (int j = 0; j < 8; ++j) u[j] = *(const uint*)(base + sIdx[wv][i + j]);
#pragma unroll
      for (int j = 0; j < 8; j += 2) {
        a00 += bfLo(u[j]);
        a01 += bfHi(u[j]);
        a10 += bfLo(u[j + 1]);
        a11 += bfHi(u[j + 1]);
      }
    }
    for (; i < rem; ++i) {
      uint u = *(const uint*)(base + sIdx[wv][i]);
      a00 += bfLo(u);
      a01 += bfHi(u);
    }
  }

  float wdn = wg[0] * dinv[n], bb = bg[0];
  float v0 = wdn * (a00 + a10) + bb;
  float v1 = wdn * (a01 + a11) + bb;
  v0 = LRELU(v0);
  v1 = LRELU(v1);
  uint pk = (uint)f2bf(v0) | ((uint)f2bf(v1) << 16);
  *(uint*)&gcnT[(size_t)chunk * KPAD * 128 + (size_t)n * 128 + 2 * l] = pk;
}

// ---------- MFMA GEMM v2: 128x128 tile, BK=32, 4 waves (2x2) x 4x4 frags ----------
// A chunk-strided: base = (m0/pw)*pstride + m0%pw, row stride lda.
// LDS rows permuted: k-row k -> p = (k&7)*4 + (k>>3); stride LSTR=144 u16.
template <bool SPLITK>
__global__ __launch_bounds__(256) void mfma_gemm2(const ushort* __restrict__ AT, int lda, int pw,
                                                  size_t pstride, const float* __restrict__ B,
                                                  int ldb, int KB, int Nv, int iters,
                                                  float* __restrict__ C, int ldc,
                                                  const float* __restrict__ bias) {
  __shared__ ushort As[32 * LSTR];
  __shared__ ushort Bs[32 * LSTR];
  int n0 = blockIdx.x * 128, m0 = blockIdx.y * 128;
  int k0 = blockIdx.z * iters * 32;
  int tid = threadIdx.x;
  int kr = tid >> 4, c8 = (tid & 15) * 8;  // staging: k-row, 8-col group
  int l = tid & 63, w = tid >> 6;
  int wr = w >> 1, wc = w & 1;             // wave quadrant (64x64 each)
  int lrow = l & 15, lkg = l >> 4;         // frag row, k-group
  const ushort* Ap = AT + (size_t)(m0 / pw) * pstride + (m0 % pw);
  f32x4 acc[4][4] = {};

  for (int kt = 0; kt < iters; ++kt) {
    int kg = k0 + kt * 32;
    // A: rows kr, kr+16 (16B each)
    uint4 av0 = *(const uint4*)&Ap[(size_t)(kg + kr) * lda + c8];
    uint4 av1 = *(const uint4*)&Ap[(size_t)(kg + kr + 16) * lda + c8];
    // B: rows kr, kr+16, f32->bf16, guarded
    uint4 bv0 = {0u, 0u, 0u, 0u}, bv1 = {0u, 0u, 0u, 0u};
    int col = n0 + c8;
    if (col < Nv) {
      if (kg + kr < KB) {
        const float4* bp = (const float4*)(B + (size_t)(kg + kr) * ldb + col);
        float4 f0 = bp[0], f1 = bp[1];
        bv0.x = (uint)f2bf(f0.x) | ((uint)f2bf(f0.y) << 16);
        bv0.y = (uint)f2bf(f0.z) | ((uint)f2bf(f0.w) << 16);
        bv0.z = (uint)f2bf(f1.x) | ((uint)f2bf(f1.y) << 16);
        bv0.w = (uint)f2bf(f1.z) | ((uint)f2bf(f1.w) << 16);
      }
      if (kg + kr + 16 < KB) {
        const float4* bp = (const float4*)(B + (size_t)(kg + kr + 16) * ldb + col);
        float4 f0 = bp[0], f1 = bp[1];
        bv1.x = (uint)f2bf(f0.x) | ((uint)f2bf(f0.y) << 16);
        bv1.y = (uint)f2bf(f0.z) | ((uint)f2bf(f0.w) << 16);
        bv1.z = (uint)f2bf(f1.x) | ((uint)f2bf(f1.y) << 16);
        bv1.w = (uint)f2bf(f1.z) | ((uint)f2bf(f1.w) << 16);
      }
    }
    __syncthreads();
    {
      int p0 = (kr & 7) * 4 + (kr >> 3);          // permuted row for kr
      int p1 = ((kr + 16) & 7) * 4 + ((kr + 16) >> 3);
      *(uint4*)&As[p0 * LSTR + c8] = av0;
      *(uint4*)&As[p1 * LSTR + c8] = av1;
      *(uint4*)&Bs[p0 * LSTR + c8] = bv0;
      *(uint4*)&Bs[p1 * LSTR + c8] = bv1;
    }
    __syncthreads();
    // fragments: k = lkg*8 + j  ->  permuted row 4j + lkg
    short8 a[4], b[4];
#pragma unroll
    for (int j = 0; j < 8; ++j) {
      int pr = (4 * j + lkg) * LSTR;
#pragma unroll
      for (int mi = 0; mi < 4; ++mi) a[mi][j] = (short)As[pr + wr * 64 + mi * 16 + lrow];
#pragma unroll
      for (int nj = 0; nj < 4; ++nj) b[nj][j] = (short)Bs[pr + wc * 64 + nj * 16 + lrow];
    }
#pragma unroll
    for (int mi = 0; mi < 4; ++mi)
#pragma unroll
      for (int nj = 0; nj < 4; ++nj)
        acc[mi][nj] = __builtin_amdgcn_mfma_f32_16x16x32_bf16(a[mi], b[nj], acc[mi][nj], 0, 0, 0);
  }

  // epilogue: D col = lane&15, row = (lane>>4)*4 + r
#pragma unroll
  for (int mi = 0; mi < 4; ++mi)
#pragma unroll
    for (int nj = 0; nj < 4; ++nj)
#pragma unroll
      for (int r = 0; r < 4; ++r) {
        int row = m0 + wr * 64 + mi * 16 + lkg * 4 + r;
        int col = n0 + wc * 64 + nj * 16 + lrow;
        if (SPLITK) {
          atomicAdd(&C[(size_t)row * ldc + col], acc[mi][nj][r]);
        } else if (col < Nv) {
          float v = acc[mi][nj][r] + bias[col];
          C[(size_t)row * ldc + col] = LRELU(v);
        }
      }
}

// ---------- tail v3 (verified r9) ----------
__global__ __launch_bounds__(256) void tail2_k(
    const float* __restrict__ h1, const float* __restrict__ c1, const float* __restrict__ W2,
    const float* __restrict__ c2, const float* __restrict__ W3, const float* __restrict__ c3,
    const float* __restrict__ Wd1, const float* __restrict__ cd1, const float* __restrict__ Wd2,
    const float* __restrict__ cd2, const float* __restrict__ Wg1, const float* __restrict__ cg1,
    const float* __restrict__ Wg2, const float* __restrict__ cg2, const float* __restrict__ Wg3,
    const float* __restrict__ cg3, float* __restrict__ out_z, float* __restrict__ out_d,
    ushort* __restrict__ d2bfT, int BT, int b0) {
  __shared__ float s_h1[512];
  __shared__ float s_h2[256];
  __shared__ float s_z[64];
  __shared__ float s_d1[256];
  __shared__ float s_g1[256];
  __shared__ float s_g2[256];
  __shared__ float s_part[4][256];
  __shared__ float s_red[4];
  int rl = blockIdx.x;
  int rg = b0 + rl;
  int t = threadIdx.x;
  int w = t >> 6, l = t & 63;

  {
    float r0 = h1[(size_t)rl * 512 + t] + c1[t];
    float r1 = h1[(size_t)rl * 512 + t + 256] + c1[t + 256];
    s_h1[t] = LRELU(r0);
    s_h1[t + 256] = LRELU(r1);
  }
  __syncthreads();

  {
    int c4 = l * 4;
    float a0 = 0.f, a1 = 0.f, a2 = 0.f, a3 = 0.f;
#pragma unroll 8
    for (int k = w * 128; k < w * 128 + 128; ++k) {
      float4 wv = *(const float4*)&W2[(size_t)k * 256 + c4];
      float x = s_h1[k];
      a0 += x * wv.x; a1 += x * wv.y; a2 += x * wv.z; a3 += x * wv.w;
    }
    float4 pv = {a0, a1, a2, a3};
    *(float4*)&s_part[w][c4] = pv;
  }
  __syncthreads();
  s_h2[t] = LRELU(s_part[0][t] + s_part[1][t] + s_part[2][t] + s_part[3][t] + c2[t]);
  __syncthreads();

  {
    int c = t >> 2, p = t & 3;
    float a = 0.f;
#pragma unroll 8
    for (int k = p * 64; k < p * 64 + 64; ++k) a += s_h2[k] * W3[(size_t)k * 64 + c];
    s_part[p][c] = a;
  }
  __syncthreads();
  if (t < 64) {
    float v = s_part[0][t] + s_part[1][t] + s_part[2][t] + s_part[3][t] + c3[t];
    v = LRELU(v);
    s_z[t] = v;
    out_z[(size_t)rg * 64 + t] = v;
  }
  __syncthreads();

  {
    float a = 0.f;
#pragma unroll
    for (int k = 0; k < 64; ++k) a += s_z[k] * Wd1[(size_t)k * 256 + t];
    s_d1[t] = LRELU(a + cd1[t]);
  }
  {
    float a = 0.f;
#pragma unroll
    for (int k = 0; k < 64; ++k) a += s_z[k] * Wg1[(size_t)k * 256 + t];
    s_g1[t] = LRELU(a + cg1[t]);
  }
  __syncthreads();

  {
    int g = t & 127, p = t >> 7;
    int c4 = g * 4;
    float a0 = 0.f, a1 = 0.f, a2 = 0.f, a3 = 0.f;
#pragma unroll 8
    for (int k = p * 128; k < p * 128 + 128; ++k) {
      float4 wv = *(const float4*)&Wd2[(size_t)k * 512 + c4];
      float x = s_d1[k];
      a0 += x * wv.x; a1 += x * wv.y; a2 += x * wv.z; a3 += x * wv.w;
    }
    float* sp = &s_part[0][0];
    float4 pv = {a0, a1, a2, a3};
    *(float4*)&sp[p * 512 + c4] = pv;
  }
  __syncthreads();
  {
    const float* sp = &s_part[0][0];
#pragma unroll
    for (int cc = 0; cc < 2; ++cc) {
      int c = t + cc * 256;
      float v = sp[c] + sp[512 + c] + cd2[c];
      v = LRELU(v);
      d2bfT[(size_t)c * BT + rl] = f2bf(v);
    }
  }
  __syncthreads();

  {
    int c4 = l * 4;
    float a0 = 0.f, a1 = 0.f, a2 = 0.f, a3 = 0.f;
#pragma unroll 8
    for (int k = w * 64; k < w * 64 + 64; ++k) {
      float4 wv = *(const float4*)&Wg2[(size_t)k * 256 + c4];
      float x = s_g1[k];
      a0 += x * wv.x; a1 += x * wv.y; a2 += x * wv.z; a3 += x * wv.w;
    }
    float4 pv = {a0, a1, a2, a3};
    *(float4*)&s_part[w][c4] = pv;
  }
  __syncthreads();
  s_g2[t] = LRELU(s_part[0][t] + s_part[1][t] + s_part[2][t] + s_part[3][t] + cg2[t]);
  __syncthreads();

  {
    float p = s_g2[t] * Wg3[t];
#pragma unroll
    for (int o = 32; o > 0; o >>= 1) p += __shfl_down(p, o);
    if ((t & 63) == 0) s_red[t >> 6] = p;
    __syncthreads();
    if (t == 0) {
      float s = s_red[0] + s_red[1] + s_red[2] + s_red[3] + cg3[0];
      out_d[rg] = 1.f / (1.f + __expf(-s));
    }
  }
}

// ---------- sentinels ----------
__global__ void sentinel_k(float* out, float val) { out[0] = val; }
__global__ void flag_sentinel_k(float* out, const int* flag) {
  if (*flag != 0) out[0] = 70000.0f;
}

extern "C" void kernel_launch(void* const* d_in, const int* in_sizes, int n_in,
                              void* d_out, int out_size, void* d_ws, size_t ws_size,
                              hipStream_t stream) {
  const float* data = (const float*)d_in[0];
  const float* noise = (const float*)d_in[1];
  const int* edge = (const int*)d_in[2];
  const int* esrc_in = edge;
  const int* edst_in = edge + Ee;
  const float* w_gcn = (const float*)d_in[3];
  const float* b_gcn = (const float*)d_in[4];
  const float* enc1_w = (const float*)d_in[5];
  const float* enc1_b = (const float*)d_in[6];
  const float* enc2_w = (const float*)d_in[7];
  const float* enc2_b = (const float*)d_in[8];
  const float* enc3_w = (const float*)d_in[9];
  const float* enc3_b = (const float*)d_in[10];
  const float* dec1_w = (const float*)d_in[11];
  const float* dec1_b = (const float*)d_in[12];
  const float* dec2_w = (const float*)d_in[13];
  const float* dec2_b = (const float*)d_in[14];
  const float* dec3_w = (const float*)d_in[15];
  const float* dec3_b = (const float*)d_in[16];
  const float* disc1_w = (const float*)d_in[17];
  const float* disc1_b = (const float*)d_in[18];
  const float* disc2_w = (const float*)d_in[19];
  const float* disc2_b = (const float*)d_in[20];
  const float* disc3_w = (const float*)d_in[21];
  const float* disc3_b = (const float*)d_in[22];

  int BT = 128;
  if (ws_size >= 48500000u) BT = 512;
  else if (ws_size >= 24392500u) BT = 256;
  int NC = BT / 128;
  if (NC < 1) NC = 1;

  char* w = (char*)d_ws;
  size_t o = 0;
  auto alloc = [&](size_t bytes) {
    size_t r = o;
    o = (o + bytes + 15) & ~(size_t)15;
    return r;
  };
  ushort* xs = (ushort*)(w + alloc((size_t)Nn * BT * 2));
  ushort* gcnT = (ushort*)(w + alloc((size_t)KPAD * BT * 2));
  float* h1 = (float*)(w + alloc((size_t)BT * 512 * 4));
  ushort* d2bfT = (ushort*)(w + alloc((size_t)512 * BT * 2));
  float* dinv = (float*)(w + alloc(Nn * 4));
  int* cnt = (int*)(w + alloc(Nn * 4));
  int* offs = (int*)(w + alloc(Nn * 4));
  int* cursor = (int*)(w + alloc(Nn * 4));
  uint* eOff = (uint*)(w + alloc(Ee * 4));
  int* flag = (int*)(w + alloc(16));

  float* outp = (float*)d_out;
  float* out_dec = outp;
  float* out_z = outp + (size_t)Bb * Nn;
  float* out_d = out_z + (size_t)Bb * 64;

  static const int expect_sizes[23] = {
      10240000, 10240000, 1280000, 1, 1,
      10240000, 512, 131072, 256, 16384, 64,
      16384, 256, 131072, 512, 10240000, 20000,
      16384, 256, 65536, 256, 256, 1};
  float host_sentinel = 0.f;
  if (n_in != 23) host_sentinel = 50000.f;
  else if (out_size != 10273280) host_sentinel = 80000.f;
  else {
    for (int i = 0; i < 23; ++i)
      if (in_sizes[i] != expect_sizes[i]) { host_sentinel = 100000.f + 1000.f * i; break; }
  }

  // ---- CSR build (once) ----
  hipMemsetAsync(cnt, 0, Nn * sizeof(int), stream);
  hipMemsetAsync(flag, 0, 2 * sizeof(int), stream);
  hist_check_k<<<(Ee + 255) / 256, 256, 0, stream>>>(esrc_in, edst_in, Ee, cnt, flag);
  offs_k<<<(Nn + 255) / 256, 256, 0, stream>>>(cnt, offs, cursor, dinv, flag + 1);
  scatter_k<<<(Ee + 255) / 256, 256, 0, stream>>>(esrc_in, edst_in, Ee, cursor, eOff);
  hipMemsetAsync(gcnT, 0, (size_t)KPAD * BT * 2, stream);

  // ---- per batch-tile pipeline ----
  for (int b0 = 0; b0 < Bb; b0 += BT) {
    {
      dim3 g((Nn + 63) / 64, BT / 64);
      transpose_xs_k<<<g, 256, 0, stream>>>(data, noise, dinv, xs, b0);
    }
    spmm_chunk_k<<<(Nn / 4) * NC, 256, 0, stream>>>(xs, eOff, offs, cnt, dinv, w_gcn, b_gcn,
                                                    gcnT, NC);
    hipMemsetAsync(h1, 0, (size_t)BT * 512 * 4, stream);
    {
      // enc1: M=BT N=512 K=20000(pad 20480), splitK 32 x (20 x 32)
      dim3 g(512 / 128, BT / 128, 32);
      mfma_gemm2<true><<<g, 256, 0, stream>>>(gcnT, 128, 128, (size_t)KPAD * 128, enc1_w, 512,
                                              Nn, 512, 20, h1, 512, nullptr);
    }
    tail2_k<<<BT, 256, 0, stream>>>(h1, enc1_b, enc2_w, enc2_b, enc3_w, enc3_b, dec1_w, dec1_b,
                                    dec2_w, dec2_b, disc1_w, disc1_b, disc2_w, disc2_b, disc3_w,
                                    disc3_b, out_z, out_d, d2bfT, BT, b0);
    {
      // dec3: M=BT N=20000 K=512 (16 x 32)
      dim3 g((Nn + 127) / 128, BT / 128, 1);
      mfma_gemm2<false><<<g, 256, 0, stream>>>(d2bfT, BT, BT, 0, dec3_w, Nn, 512, Nn, 16,
                                               out_dec + (size_t)b0 * Nn, Nn, dec3_b);
    }
  }

  flag_sentinel_k<<<1, 1, 0, stream>>>(out_dec, flag);
  if (host_sentinel != 0.f) sentinel_k<<<1, 1, 0, stream>>>(out_dec, host_sentinel);
}